// Round 1
// baseline (1289.861 us; speedup 1.0000x reference)
//
#include <hip/hip_runtime.h>
#include <math.h>

// TreeMambaLayer: B=4, N=2048, D_MODEL=768, D_INNER=1536, DT_RANK=48
// Round 1: correct fp32 baseline. GEMMs on vector ALU (no fp32 MFMA on CDNA4).
// Recurrence: on-device level scheduling (Wyllie depth + counting sort), then
// block-owned-columns level sweep with only __syncthreads between levels.

#define ROWS 8192
#define DIN 1536
#define DMOD 768
#define NSEQ 2048
#define DTR 48

// ---------------------------------------------------------------- GEMM (fp32)
// 128x128 tile, BK=16, 256 threads, 8x8 per thread.
// MODE 0: plain C := A@B (C0, ld=N)
// MODE 1: in_proj: cols<1536 -> XI (C0), cols>=1536 -> silu -> Z (C1), ld=1536
template <int MODE>
__global__ __launch_bounds__(256) void gemm_kernel(
    const float* __restrict__ A, const float* __restrict__ B,
    float* __restrict__ C0, float* __restrict__ C1, int K, int N) {
  __shared__ float As[16][128];
  __shared__ float Bs[16][128];
  const int tid = threadIdx.x;
  const int tx = tid & 15, ty = tid >> 4;
  const int row0 = blockIdx.y * 128, col0 = blockIdx.x * 128;

  float acc[8][8];
#pragma unroll
  for (int i = 0; i < 8; i++)
#pragma unroll
    for (int j = 0; j < 8; j++) acc[i][j] = 0.f;

  for (int k0 = 0; k0 < K; k0 += 16) {
#pragma unroll
    for (int h = 0; h < 2; h++) {
      const int r = (tid >> 2) + h * 64;
      const int c = (tid & 3) << 2;
      const float4 v = *(const float4*)(A + (size_t)(row0 + r) * K + k0 + c);
      As[c + 0][r] = v.x;
      As[c + 1][r] = v.y;
      As[c + 2][r] = v.z;
      As[c + 3][r] = v.w;
    }
#pragma unroll
    for (int h = 0; h < 2; h++) {
      const int kr = (tid >> 5) + h * 8;
      const int c = (tid & 31) << 2;
      *(float4*)(&Bs[kr][c]) = *(const float4*)(B + (size_t)(k0 + kr) * N + col0 + c);
    }
    __syncthreads();
#pragma unroll
    for (int k = 0; k < 16; k++) {
      float a[8], b[8];
      *(float4*)&a[0] = *(const float4*)&As[k][ty * 8];
      *(float4*)&a[4] = *(const float4*)&As[k][ty * 8 + 4];
      *(float4*)&b[0] = *(const float4*)&Bs[k][tx * 8];
      *(float4*)&b[4] = *(const float4*)&Bs[k][tx * 8 + 4];
#pragma unroll
      for (int i = 0; i < 8; i++)
#pragma unroll
        for (int j = 0; j < 8; j++) acc[i][j] = fmaf(a[i], b[j], acc[i][j]);
    }
    __syncthreads();
  }

  if (MODE == 0) {
#pragma unroll
    for (int i = 0; i < 8; i++) {
      const int gr = row0 + ty * 8 + i;
      const int gc = col0 + tx * 8;
      float4 v0 = make_float4(acc[i][0], acc[i][1], acc[i][2], acc[i][3]);
      float4 v1 = make_float4(acc[i][4], acc[i][5], acc[i][6], acc[i][7]);
      *(float4*)(C0 + (size_t)gr * N + gc) = v0;
      *(float4*)(C0 + (size_t)gr * N + gc + 4) = v1;
    }
  } else {
    const bool is_z = (col0 >= DIN);
#pragma unroll
    for (int i = 0; i < 8; i++) {
      const int gr = row0 + ty * 8 + i;
      const int gc = col0 + tx * 8;
      if (!is_z) {
        float4 v0 = make_float4(acc[i][0], acc[i][1], acc[i][2], acc[i][3]);
        float4 v1 = make_float4(acc[i][4], acc[i][5], acc[i][6], acc[i][7]);
        *(float4*)(C0 + (size_t)gr * DIN + gc) = v0;
        *(float4*)(C0 + (size_t)gr * DIN + gc + 4) = v1;
      } else {
        float s[8];
#pragma unroll
        for (int j = 0; j < 8; j++) {
          const float v = acc[i][j];
          s[j] = v / (1.0f + __expf(-v));  // silu
        }
        float4 v0 = make_float4(s[0], s[1], s[2], s[3]);
        float4 v1 = make_float4(s[4], s[5], s[6], s[7]);
        *(float4*)(C1 + (size_t)gr * DIN + gc - DIN) = v0;
        *(float4*)(C1 + (size_t)gr * DIN + gc + 4 - DIN) = v1;
      }
    }
  }
}

// ------------------------------------------------- x_dbl = x_inner @ x_proj_w
// out cols: [0..47] dt_lr, 48 -> Bc, 49 -> Cc. Block: 64 rows, 256 threads.
__global__ __launch_bounds__(256) void xdbl_kernel(
    const float* __restrict__ XI, const float* __restrict__ W,  // 1536 x 50
    float* __restrict__ DTLR, float* __restrict__ BC, float* __restrict__ CC) {
  __shared__ float As[32][65];
  __shared__ float Ws[32][52];
  const int tid = threadIdx.x;
  const int row0 = blockIdx.x * 64;
  const int r = tid & 63, cg = tid >> 6;  // col group: cols cg + 4*j

  float acc[13];
#pragma unroll
  for (int j = 0; j < 13; j++) acc[j] = 0.f;

  for (int k0 = 0; k0 < DIN; k0 += 32) {
#pragma unroll
    for (int h = 0; h < 2; h++) {
      const int rr = (tid >> 3) + h * 32;
      const int c = (tid & 7) << 2;
      const float4 v = *(const float4*)(XI + (size_t)(row0 + rr) * DIN + k0 + c);
      As[c + 0][rr] = v.x;
      As[c + 1][rr] = v.y;
      As[c + 2][rr] = v.z;
      As[c + 3][rr] = v.w;
    }
    for (int idx = tid; idx < 32 * 52; idx += 256) {
      const int kk = idx / 52, c = idx % 52;
      Ws[kk][c] = (c < 50) ? W[(size_t)(k0 + kk) * 50 + c] : 0.f;
    }
    __syncthreads();
#pragma unroll
    for (int k = 0; k < 32; k++) {
      const float a = As[k][r];
#pragma unroll
      for (int j = 0; j < 13; j++) acc[j] = fmaf(a, Ws[k][cg + 4 * j], acc[j]);
    }
    __syncthreads();
  }
  const int row = row0 + r;
#pragma unroll
  for (int j = 0; j < 13; j++) {
    const int c = cg + 4 * j;
    if (c < 48)
      DTLR[(size_t)row * DTR + c] = acc[j];
    else if (c == 48)
      BC[row] = acc[j];
    else if (c == 49)
      CC[row] = acc[j];
  }
}

// ----------------------------------- dt = softplus(dt_lr @ dt_proj_w + bias);
// dA = exp(dt * -exp(A_log)); dBx = dt * Bc * x_inner  (written to H buffer)
__global__ __launch_bounds__(256) void dt_kernel(
    const float* __restrict__ DTLR, const float* __restrict__ Wdt,  // 48x1536
    const float* __restrict__ bias, const float* __restrict__ A_log,
    const float* __restrict__ BC, const float* __restrict__ XI,
    float* __restrict__ DA, float* __restrict__ DBX) {
  __shared__ float Lr[16][48];
  __shared__ float Wls[48][256];
  const int tid = threadIdx.x;
  const int row0 = blockIdx.x << 4;
  for (int idx = tid; idx < 16 * 48; idx += 256) {
    const int rr = idx / 48, c = idx % 48;
    Lr[rr][c] = DTLR[(size_t)(row0 + rr) * DTR + c];
  }
  for (int d0 = 0; d0 < DIN; d0 += 256) {
#pragma unroll
    for (int k = 0; k < 48; k++) Wls[k][tid] = Wdt[(size_t)k * DIN + d0 + tid];
    __syncthreads();
    const int d = d0 + tid;
    const float bs = bias[d];
    const float Ad = -__expf(A_log[d]);
    float wv[48];
#pragma unroll
    for (int k = 0; k < 48; k++) wv[k] = Wls[k][tid];
#pragma unroll 2
    for (int rr = 0; rr < 16; rr++) {
      float s = bs;
#pragma unroll
      for (int k = 0; k < 48; k++) s = fmaf(Lr[rr][k], wv[k], s);
      // stable softplus: max(s,0) + log1p(exp(-|s|))
      const float sp = fmaxf(s, 0.f) + log1pf(__expf(-fabsf(s)));
      const int row = row0 + rr;
      DA[(size_t)row * DIN + d] = __expf(sp * Ad);
      DBX[(size_t)row * DIN + d] = sp * BC[row] * XI[(size_t)row * DIN + d];
    }
    __syncthreads();
  }
}

// -------------------------------------------------- level schedule (1 block)
// depth via Wyllie pointer doubling (11 rounds covers depth<=2047), histogram,
// inclusive scan, scatter into level-sorted slots.
__global__ __launch_bounds__(1024) void sched_kernel(
    const int* __restrict__ sidx, const int* __restrict__ spar,
    int* __restrict__ SLOT_NODE, int* __restrict__ SLOT_PNODE,
    int* __restrict__ LSTART, int* __restrict__ NLEV) {
  __shared__ int par[2048], idx[2048], ancA[2048], ancB[2048], rnkA[2048], rnkB[2048];
  __shared__ int dmax;
  const int tid = threadIdx.x;
  for (int i = tid; i < 2048; i += 1024) {
    const int p = spar[i];
    par[i] = p;
    idx[i] = sidx[i];
    ancA[i] = (p < 0) ? -1 : p;
    rnkA[i] = (p < 0) ? 0 : 1;
  }
  if (tid == 0) dmax = 0;
  __syncthreads();
  for (int r = 0; r < 11; r++) {
    int* ca = (r & 1) ? ancB : ancA;
    int* cr = (r & 1) ? rnkB : rnkA;
    int* na = (r & 1) ? ancA : ancB;
    int* nr = (r & 1) ? rnkA : rnkB;
    for (int i = tid; i < 2048; i += 1024) {
      const int a = ca[i], rv = cr[i];
      if (a >= 0) {
        nr[i] = rv + cr[a];
        na[i] = ca[a];
      } else {
        nr[i] = rv;
        na[i] = a;
      }
    }
    __syncthreads();
  }
  // depth now in rnkB. histogram into ancA.
  for (int i = tid; i < 2048; i += 1024) ancA[i] = 0;
  __syncthreads();
  for (int i = tid; i < 2048; i += 1024) {
    atomicAdd(&ancA[rnkB[i]], 1);
    atomicMax(&dmax, rnkB[i]);
  }
  __syncthreads();
  // inclusive scan (Hillis-Steele, 11 steps) -> ends in ancB
  for (int s = 0; s < 11; s++) {
    const int off = 1 << s;
    int* cur = (s & 1) ? ancB : ancA;
    int* nxt = (s & 1) ? ancA : ancB;
    for (int i = tid; i < 2048; i += 1024) {
      int v = cur[i];
      if (i >= off) v += cur[i - off];
      nxt[i] = v;
    }
    __syncthreads();
  }
  for (int i = tid; i < 2049; i += 1024) {
    const int v = (i == 0) ? 0 : ancB[i - 1];
    LSTART[i] = v;
    if (i < 2048) rnkA[i] = v;  // running cursor per level
  }
  if (tid == 0) NLEV[0] = dmax + 1;
  __syncthreads();
  for (int i = tid; i < 2048; i += 1024) {
    const int d = rnkB[i];
    const int slot = atomicAdd(&rnkA[d], 1);
    SLOT_NODE[slot] = idx[i];
    const int p = par[i];
    SLOT_PNODE[slot] = (p < 0) ? -1 : idx[p];
  }
}

// ------------------------------------------------------------ tree recurrence
// 384 blocks x 256 threads; block owns 4 float4-columns exclusively -> only
// __syncthreads between levels. H holds dBx on entry, h on exit (in-place).
__global__ __launch_bounds__(256) void recur_kernel(
    const float* __restrict__ DA, float* __restrict__ H,
    const int* __restrict__ SLOT_NODE, const int* __restrict__ SLOT_PNODE,
    const int* __restrict__ LSTART, const int* __restrict__ NLEV) {
  const int tid = threadIdx.x;
  const int base_c4 = blockIdx.x * 4;  // 384 * 4 = 1536 float4 columns
  const int nlev = NLEV[0];
  const float4* DA4 = (const float4*)DA;
  float4* H4 = (float4*)H;
  for (int L = 0; L < nlev; L++) {
    const int s0 = LSTART[L], s1 = LSTART[L + 1];
    const int items = (s1 - s0) * 4;
    for (int it = tid; it < items; it += 256) {
      const int s = s0 + (it >> 2);
      const int c4 = base_c4 + (it & 3);
      const int node = SLOT_NODE[s];
      const int pn = SLOT_PNODE[s];
      const int b = c4 / 384, d4 = c4 % 384;
      const size_t ib = ((size_t)b * NSEQ + node) * 384 + d4;
      const float4 a = DA4[ib];
      const float4 xv = H4[ib];
      float4 hp = make_float4(0.f, 0.f, 0.f, 0.f);
      if (pn >= 0) hp = H4[((size_t)b * NSEQ + pn) * 384 + d4];
      float4 hv;
      hv.x = fmaf(a.x, hp.x, xv.x);
      hv.y = fmaf(a.y, hp.y, xv.y);
      hv.z = fmaf(a.z, hp.z, xv.z);
      hv.w = fmaf(a.w, hp.w, xv.w);
      H4[ib] = hv;
    }
    __syncthreads();
  }
}

// --------------------------------------------- y, layernorm, z-gate -> YLN
__global__ __launch_bounds__(256) void ln_kernel(
    const float* __restrict__ H, const float* __restrict__ CC,
    const float* __restrict__ XI, const float* __restrict__ Dp,
    const float* __restrict__ gamma, const float* __restrict__ beta,
    const float* __restrict__ Z, float* __restrict__ YLN) {
  const int row = blockIdx.x;
  const int tid = threadIdx.x;
  const float C = CC[row];
  const float* hrow = H + (size_t)row * DIN;
  const float* xrow = XI + (size_t)row * DIN;
  float y[6];
  float s = 0.f, s2 = 0.f;
#pragma unroll
  for (int i = 0; i < 6; i++) {
    const int d = tid + i * 256;
    const float v = fmaf(hrow[d], C, Dp[d] * xrow[d]);
    y[i] = v;
    s += v;
    s2 = fmaf(v, v, s2);
  }
#pragma unroll
  for (int off = 32; off >= 1; off >>= 1) {
    s += __shfl_down(s, off);
    s2 += __shfl_down(s2, off);
  }
  __shared__ float rs[4], rs2[4];
  const int w = tid >> 6;
  if ((tid & 63) == 0) {
    rs[w] = s;
    rs2[w] = s2;
  }
  __syncthreads();
  const float ts = rs[0] + rs[1] + rs[2] + rs[3];
  const float ts2 = rs2[0] + rs2[1] + rs2[2] + rs2[3];
  const float mu = ts * (1.f / 1536.f);
  const float var = ts2 * (1.f / 1536.f) - mu * mu;
  const float inv = rsqrtf(var + 1e-5f);
  float* yrow = YLN + (size_t)row * DIN;
  const float* zrow = Z + (size_t)row * DIN;
#pragma unroll
  for (int i = 0; i < 6; i++) {
    const int d = tid + i * 256;
    const float o = (y[i] - mu) * inv * gamma[d] + beta[d];
    yrow[d] = o * zrow[d];
  }
}

// ---------------------------------------------------------------------- launch
extern "C" void kernel_launch(void* const* d_in, const int* in_sizes, int n_in,
                              void* d_out, int out_size, void* d_ws, size_t ws_size,
                              hipStream_t stream) {
  const float* x = (const float*)d_in[0];
  const int* sidx = (const int*)d_in[1];
  const int* spar = (const int*)d_in[2];
  const float* in_proj = (const float*)d_in[3];
  const float* x_proj = (const float*)d_in[4];
  const float* dt_proj = (const float*)d_in[5];
  const float* dt_b = (const float*)d_in[6];
  const float* A_log = (const float*)d_in[7];
  const float* Dp = (const float*)d_in[8];
  const float* gamma = (const float*)d_in[9];
  const float* beta = (const float*)d_in[10];
  const float* out_proj = (const float*)d_in[11];
  float* out = (float*)d_out;

  float* ws = (float*)d_ws;
  const size_t RC = (size_t)ROWS * DIN;  // 12,582,912 floats
  float* XI = ws;                        // x_inner
  float* Z = ws + RC;                    // silu(z)
  float* DA = ws + 2 * RC;               // dA, later reused as YLN
  float* H = ws + 3 * RC;                // dBx -> h (in place)
  float* DTLR = ws + 4 * RC;             // 8192*48
  float* BC = DTLR + (size_t)ROWS * DTR;
  float* CC = BC + ROWS;
  int* ipart = (int*)(CC + ROWS);
  int* SLOT_NODE = ipart;
  int* SLOT_PNODE = ipart + 2048;
  int* LSTART = ipart + 4096;
  int* NLEV = ipart + 4096 + 2049;
  // total ws use: ~203 MB

  sched_kernel<<<1, 1024, 0, stream>>>(sidx, spar, SLOT_NODE, SLOT_PNODE, LSTART, NLEV);
  gemm_kernel<1><<<dim3(24, 64), 256, 0, stream>>>(x, in_proj, XI, Z, DMOD, 2 * DIN);
  xdbl_kernel<<<128, 256, 0, stream>>>(XI, x_proj, DTLR, BC, CC);
  dt_kernel<<<512, 256, 0, stream>>>(DTLR, dt_proj, dt_b, A_log, BC, XI, DA, H);
  recur_kernel<<<384, 256, 0, stream>>>(DA, H, SLOT_NODE, SLOT_PNODE, LSTART, NLEV);
  ln_kernel<<<ROWS, 256, 0, stream>>>(H, CC, XI, Dp, gamma, beta, Z, DA);
  gemm_kernel<0><<<dim3(6, 64), 256, 0, stream>>>(DA, out_proj, out, nullptr, DIN, DMOD);
}

// Round 2
// 650.235 us; speedup vs baseline: 1.9837x; 1.9837x over previous
//
#include <hip/hip_runtime.h>
#include <math.h>

// TreeMambaLayer: B=4, N=2048, D_MODEL=768, D_INNER=1536, DT_RANK=48
// Round 2: big GEMMs -> bf16 MFMA (m97 structure: 128x128 tile, BK=32,
// global_load_lds width=16, B^T weights, 16x16x32 bf16 MFMA, fp32 epilogue).

#define ROWS 8192
#define DIN 1536
#define DMOD 768
#define NSEQ 2048
#define DTR 48

typedef __bf16 bfrag __attribute__((ext_vector_type(8)));
typedef float f4 __attribute__((ext_vector_type(4)));

__device__ __forceinline__ unsigned short f2bf(float f) {
  unsigned int u = __float_as_uint(f);
  unsigned int r = (u + 0x7fffu + ((u >> 16) & 1u)) >> 16;
  return (unsigned short)r;
}

__device__ __forceinline__ void gld_lds16(const void* g, void* l) {
  __builtin_amdgcn_global_load_lds((const __attribute__((address_space(1))) void*)g,
                                   (__attribute__((address_space(3))) void*)l, 16, 0, 0);
}

// ------------------------------------------------------------- bf16 MFMA GEMM
// C[M x N] = A[M x K] @ Bt[N x K]^T, A/Bt bf16 row-major, C fp32.
// MODE 0: plain store to C0 with ld = ldc.
// MODE 1: in_proj epilogue: col<1536 -> XI (C0, ld 1536), col>=1536 -> silu -> Z (C1).
template <int MODE>
__global__ __launch_bounds__(256) void mfma_gemm(
    const unsigned short* __restrict__ A, const unsigned short* __restrict__ Bt,
    float* __restrict__ C0, float* __restrict__ C1, int K, int ldc) {
  __shared__ unsigned short As[128 * 32];
  __shared__ unsigned short Bs[128 * 32];
  const int tid = threadIdx.x;
  const int w = tid >> 6, l = tid & 63;
  const int quad = l >> 4, l16 = l & 15;
  const int wrow = (w >> 1) * 64, wcol = (w & 1) * 64;
  const int row0 = blockIdx.y * 128, col0 = blockIdx.x * 128;

  f4 acc[4][4];
#pragma unroll
  for (int i = 0; i < 4; i++)
#pragma unroll
    for (int j = 0; j < 4; j++) acc[i][j] = (f4){0.f, 0.f, 0.f, 0.f};

  const int arow = row0 + w * 16 + (l >> 2);
  const int brow = col0 + w * 16 + (l >> 2);
  const int kcol = (l & 3) * 8;

  for (int k0 = 0; k0 < K; k0 += 32) {
#pragma unroll
    for (int r = 0; r < 2; r++) {
      gld_lds16(A + (size_t)(arow + r * 64) * K + k0 + kcol,
                (char*)As + r * 4096 + w * 1024);
      gld_lds16(Bt + (size_t)(brow + r * 64) * K + k0 + kcol,
                (char*)Bs + r * 4096 + w * 1024);
    }
    __syncthreads();
    bfrag af[4], bf[4];
#pragma unroll
    for (int i = 0; i < 4; i++)
      af[i] = *(const bfrag*)(const void*)(As + (wrow + i * 16 + l16) * 32 + quad * 8);
#pragma unroll
    for (int j = 0; j < 4; j++)
      bf[j] = *(const bfrag*)(const void*)(Bs + (wcol + j * 16 + l16) * 32 + quad * 8);
#pragma unroll
    for (int i = 0; i < 4; i++)
#pragma unroll
      for (int j = 0; j < 4; j++)
        acc[i][j] = __builtin_amdgcn_mfma_f32_16x16x32_bf16(af[i], bf[j], acc[i][j], 0, 0, 0);
    __syncthreads();
  }

  if (MODE == 0) {
    const int ccol = col0 + wcol + l16;
#pragma unroll
    for (int i = 0; i < 4; i++) {
      const int rb = row0 + wrow + i * 16 + quad * 4;
#pragma unroll
      for (int j = 0; j < 4; j++)
#pragma unroll
        for (int r = 0; r < 4; r++)
          C0[(size_t)(rb + r) * ldc + ccol + j * 16] = acc[i][j][r];
    }
  } else {
    const bool is_z = (col0 >= DIN);
    float* dst = is_z ? C1 : C0;
    const int cbase = col0 + wcol + l16 - (is_z ? DIN : 0);
#pragma unroll
    for (int i = 0; i < 4; i++) {
      const int rb = row0 + wrow + i * 16 + quad * 4;
#pragma unroll
      for (int j = 0; j < 4; j++)
#pragma unroll
        for (int r = 0; r < 4; r++) {
          float v = acc[i][j][r];
          if (is_z) v = v / (1.f + __expf(-v));
          dst[(size_t)(rb + r) * DIN + cbase + j * 16] = v;
        }
    }
  }
}

// ----------------------------------------------------------------- casts
__global__ __launch_bounds__(256) void cast_bf16_kernel(
    const float* __restrict__ in, unsigned short* __restrict__ out, int n4) {
  const int i = (blockIdx.x * 256 + threadIdx.x) * 4;
  if (i < n4 * 4) {
    const float4 v = *(const float4*)(in + i);
    union { unsigned short h[4]; uint2 u; } p;
    p.h[0] = f2bf(v.x);
    p.h[1] = f2bf(v.y);
    p.h[2] = f2bf(v.z);
    p.h[3] = f2bf(v.w);
    *(uint2*)(out + i) = p.u;
  }
}

// W (K x N) fp32 -> Wt (N x K) bf16
__global__ __launch_bounds__(256) void transpose_cast_kernel(
    const float* __restrict__ W, unsigned short* __restrict__ Wt, int K, int N) {
  __shared__ float t[32][33];
  const int n0 = blockIdx.x * 32, k0 = blockIdx.y * 32;
  const int tx = threadIdx.x & 31, ty = threadIdx.x >> 5;
  for (int i = ty; i < 32; i += 8) t[i][tx] = W[(size_t)(k0 + i) * N + n0 + tx];
  __syncthreads();
  for (int i = ty; i < 32; i += 8)
    Wt[(size_t)(n0 + i) * K + k0 + tx] = f2bf(t[tx][i]);
}

// ------------------------------------------------- x_dbl = x_inner @ x_proj_w
__global__ __launch_bounds__(256) void xdbl_kernel(
    const float* __restrict__ XI, const float* __restrict__ W,
    float* __restrict__ DTLR, float* __restrict__ BC, float* __restrict__ CC) {
  __shared__ float As[32][65];
  __shared__ float Ws[32][52];
  const int tid = threadIdx.x;
  const int row0 = blockIdx.x * 64;
  const int r = tid & 63, cg = tid >> 6;

  float acc[13];
#pragma unroll
  for (int j = 0; j < 13; j++) acc[j] = 0.f;

  for (int k0 = 0; k0 < DIN; k0 += 32) {
#pragma unroll
    for (int h = 0; h < 2; h++) {
      const int rr = (tid >> 3) + h * 32;
      const int c = (tid & 7) << 2;
      const float4 v = *(const float4*)(XI + (size_t)(row0 + rr) * DIN + k0 + c);
      As[c + 0][rr] = v.x;
      As[c + 1][rr] = v.y;
      As[c + 2][rr] = v.z;
      As[c + 3][rr] = v.w;
    }
    for (int idx = tid; idx < 32 * 52; idx += 256) {
      const int kk = idx / 52, c = idx % 52;
      Ws[kk][c] = (c < 50) ? W[(size_t)(k0 + kk) * 50 + c] : 0.f;
    }
    __syncthreads();
#pragma unroll
    for (int k = 0; k < 32; k++) {
      const float a = As[k][r];
#pragma unroll
      for (int j = 0; j < 13; j++) acc[j] = fmaf(a, Ws[k][cg + 4 * j], acc[j]);
    }
    __syncthreads();
  }
  const int row = row0 + r;
#pragma unroll
  for (int j = 0; j < 13; j++) {
    const int c = cg + 4 * j;
    if (c < 48)
      DTLR[(size_t)row * DTR + c] = acc[j];
    else if (c == 48)
      BC[row] = acc[j];
    else if (c == 49)
      CC[row] = acc[j];
  }
}

// ----------------------------------- dt/softplus/dA/dBx
__global__ __launch_bounds__(256) void dt_kernel(
    const float* __restrict__ DTLR, const float* __restrict__ Wdt,
    const float* __restrict__ bias, const float* __restrict__ A_log,
    const float* __restrict__ BC, const float* __restrict__ XI,
    float* __restrict__ DA, float* __restrict__ DBX) {
  __shared__ float Lr[16][48];
  __shared__ float Wls[48][256];
  const int tid = threadIdx.x;
  const int row0 = blockIdx.x << 4;
  for (int idx = tid; idx < 16 * 48; idx += 256) {
    const int rr = idx / 48, c = idx % 48;
    Lr[rr][c] = DTLR[(size_t)(row0 + rr) * DTR + c];
  }
  for (int d0 = 0; d0 < DIN; d0 += 256) {
#pragma unroll
    for (int k = 0; k < 48; k++) Wls[k][tid] = Wdt[(size_t)k * DIN + d0 + tid];
    __syncthreads();
    const int d = d0 + tid;
    const float bs = bias[d];
    const float Ad = -__expf(A_log[d]);
    float wv[48];
#pragma unroll
    for (int k = 0; k < 48; k++) wv[k] = Wls[k][tid];
#pragma unroll 2
    for (int rr = 0; rr < 16; rr++) {
      float s = bs;
#pragma unroll
      for (int k = 0; k < 48; k++) s = fmaf(Lr[rr][k], wv[k], s);
      const float sp = fmaxf(s, 0.f) + log1pf(__expf(-fabsf(s)));
      const int row = row0 + rr;
      DA[(size_t)row * DIN + d] = __expf(sp * Ad);
      DBX[(size_t)row * DIN + d] = sp * BC[row] * XI[(size_t)row * DIN + d];
    }
    __syncthreads();
  }
}

// -------------------------------------------------- level schedule (1 block)
__global__ __launch_bounds__(1024) void sched_kernel(
    const int* __restrict__ sidx, const int* __restrict__ spar,
    int* __restrict__ SLOT_NODE, int* __restrict__ SLOT_PNODE,
    int* __restrict__ LSTART, int* __restrict__ NLEV) {
  __shared__ int par[2048], idx[2048], ancA[2048], ancB[2048], rnkA[2048], rnkB[2048];
  __shared__ int dmax;
  const int tid = threadIdx.x;
  for (int i = tid; i < 2048; i += 1024) {
    const int p = spar[i];
    par[i] = p;
    idx[i] = sidx[i];
    ancA[i] = (p < 0) ? -1 : p;
    rnkA[i] = (p < 0) ? 0 : 1;
  }
  if (tid == 0) dmax = 0;
  __syncthreads();
  for (int r = 0; r < 11; r++) {
    int* ca = (r & 1) ? ancB : ancA;
    int* cr = (r & 1) ? rnkB : rnkA;
    int* na = (r & 1) ? ancA : ancB;
    int* nr = (r & 1) ? rnkA : rnkB;
    for (int i = tid; i < 2048; i += 1024) {
      const int a = ca[i], rv = cr[i];
      if (a >= 0) {
        nr[i] = rv + cr[a];
        na[i] = ca[a];
      } else {
        nr[i] = rv;
        na[i] = a;
      }
    }
    __syncthreads();
  }
  for (int i = tid; i < 2048; i += 1024) ancA[i] = 0;
  __syncthreads();
  for (int i = tid; i < 2048; i += 1024) {
    atomicAdd(&ancA[rnkB[i]], 1);
    atomicMax(&dmax, rnkB[i]);
  }
  __syncthreads();
  for (int s = 0; s < 11; s++) {
    const int off = 1 << s;
    int* cur = (s & 1) ? ancB : ancA;
    int* nxt = (s & 1) ? ancA : ancB;
    for (int i = tid; i < 2048; i += 1024) {
      int v = cur[i];
      if (i >= off) v += cur[i - off];
      nxt[i] = v;
    }
    __syncthreads();
  }
  for (int i = tid; i < 2049; i += 1024) {
    const int v = (i == 0) ? 0 : ancB[i - 1];
    LSTART[i] = v;
    if (i < 2048) rnkA[i] = v;
  }
  if (tid == 0) NLEV[0] = dmax + 1;
  __syncthreads();
  for (int i = tid; i < 2048; i += 1024) {
    const int d = rnkB[i];
    const int slot = atomicAdd(&rnkA[d], 1);
    SLOT_NODE[slot] = idx[i];
    const int p = par[i];
    SLOT_PNODE[slot] = (p < 0) ? -1 : idx[p];
  }
}

// ------------------------------------------------------------ tree recurrence
__global__ __launch_bounds__(256) void recur_kernel(
    const float* __restrict__ DA, float* __restrict__ H,
    const int* __restrict__ SLOT_NODE, const int* __restrict__ SLOT_PNODE,
    const int* __restrict__ LSTART, const int* __restrict__ NLEV) {
  const int tid = threadIdx.x;
  const int base_c4 = blockIdx.x * 4;
  const int nlev = NLEV[0];
  const float4* DA4 = (const float4*)DA;
  float4* H4 = (float4*)H;
  for (int L = 0; L < nlev; L++) {
    const int s0 = LSTART[L], s1 = LSTART[L + 1];
    const int items = (s1 - s0) * 4;
    for (int it = tid; it < items; it += 256) {
      const int s = s0 + (it >> 2);
      const int c4 = base_c4 + (it & 3);
      const int node = SLOT_NODE[s];
      const int pn = SLOT_PNODE[s];
      const int b = c4 / 384, d4 = c4 % 384;
      const size_t ib = ((size_t)b * NSEQ + node) * 384 + d4;
      const float4 a = DA4[ib];
      const float4 xv = H4[ib];
      float4 hp = make_float4(0.f, 0.f, 0.f, 0.f);
      if (pn >= 0) hp = H4[((size_t)b * NSEQ + pn) * 384 + d4];
      float4 hv;
      hv.x = fmaf(a.x, hp.x, xv.x);
      hv.y = fmaf(a.y, hp.y, xv.y);
      hv.z = fmaf(a.z, hp.z, xv.z);
      hv.w = fmaf(a.w, hp.w, xv.w);
      H4[ib] = hv;
    }
    __syncthreads();
  }
}

// --------------------------------------------- y, layernorm, z-gate -> bf16
__global__ __launch_bounds__(256) void ln_kernel(
    const float* __restrict__ H, const float* __restrict__ CC,
    const float* __restrict__ XI, const float* __restrict__ Dp,
    const float* __restrict__ gamma, const float* __restrict__ beta,
    const float* __restrict__ Z, unsigned short* __restrict__ YLN) {
  const int row = blockIdx.x;
  const int tid = threadIdx.x;
  const float C = CC[row];
  const float* hrow = H + (size_t)row * DIN;
  const float* xrow = XI + (size_t)row * DIN;
  float y[6];
  float s = 0.f, s2 = 0.f;
#pragma unroll
  for (int i = 0; i < 6; i++) {
    const int d = tid + i * 256;
    const float v = fmaf(hrow[d], C, Dp[d] * xrow[d]);
    y[i] = v;
    s += v;
    s2 = fmaf(v, v, s2);
  }
#pragma unroll
  for (int off = 32; off >= 1; off >>= 1) {
    s += __shfl_down(s, off);
    s2 += __shfl_down(s2, off);
  }
  __shared__ float rs[4], rs2[4];
  const int w = tid >> 6;
  if ((tid & 63) == 0) {
    rs[w] = s;
    rs2[w] = s2;
  }
  __syncthreads();
  const float ts = rs[0] + rs[1] + rs[2] + rs[3];
  const float ts2 = rs2[0] + rs2[1] + rs2[2] + rs2[3];
  const float mu = ts * (1.f / 1536.f);
  const float var = ts2 * (1.f / 1536.f) - mu * mu;
  const float inv = rsqrtf(var + 1e-5f);
  unsigned short* yrow = YLN + (size_t)row * DIN;
  const float* zrow = Z + (size_t)row * DIN;
#pragma unroll
  for (int i = 0; i < 6; i++) {
    const int d = tid + i * 256;
    const float o = (y[i] - mu) * inv * gamma[d] + beta[d];
    yrow[d] = f2bf(o * zrow[d]);
  }
}

// ---------------------------------------------------------------------- launch
extern "C" void kernel_launch(void* const* d_in, const int* in_sizes, int n_in,
                              void* d_out, int out_size, void* d_ws, size_t ws_size,
                              hipStream_t stream) {
  const float* x = (const float*)d_in[0];
  const int* sidx = (const int*)d_in[1];
  const int* spar = (const int*)d_in[2];
  const float* in_proj = (const float*)d_in[3];
  const float* x_proj = (const float*)d_in[4];
  const float* dt_proj = (const float*)d_in[5];
  const float* dt_b = (const float*)d_in[6];
  const float* A_log = (const float*)d_in[7];
  const float* Dp = (const float*)d_in[8];
  const float* gamma = (const float*)d_in[9];
  const float* beta = (const float*)d_in[10];
  const float* out_proj = (const float*)d_in[11];
  float* out = (float*)d_out;

  float* ws = (float*)d_ws;
  const size_t RC = (size_t)ROWS * DIN;  // 12,582,912 floats
  float* XI = ws;                        // x_inner fp32
  float* Z = ws + RC;                    // silu(z) fp32
  float* DA = ws + 2 * RC;               // dA fp32; later reused as YLN (bf16)
  float* H = ws + 3 * RC;                // dBx -> h (in place)
  float* DTLR = ws + 4 * RC;             // 8192*48
  float* BC = DTLR + (size_t)ROWS * DTR;
  float* CC = BC + ROWS;
  int* ipart = (int*)(CC + ROWS);
  int* SLOT_NODE = ipart;
  int* SLOT_PNODE = ipart + 2048;
  int* LSTART = ipart + 4096;
  int* NLEV = ipart + 4096 + 2049;
  unsigned short* Xbf = (unsigned short*)(ipart + 8192);        // 8192x768 bf16
  unsigned short* W1t = Xbf + (size_t)ROWS * DMOD;              // 3072x768 bf16
  unsigned short* W2t = W1t + (size_t)(2 * DIN) * DMOD;         // 768x1536 bf16
  unsigned short* YLN = (unsigned short*)DA;                    // 8192x1536 bf16
  // total ws use: ~223 MB

  sched_kernel<<<1, 1024, 0, stream>>>(sidx, spar, SLOT_NODE, SLOT_PNODE, LSTART, NLEV);
  cast_bf16_kernel<<<(ROWS * DMOD / 4 + 255) / 256, 256, 0, stream>>>(x, Xbf, ROWS * DMOD / 4);
  transpose_cast_kernel<<<dim3(2 * DIN / 32, DMOD / 32), 256, 0, stream>>>(in_proj, W1t, DMOD, 2 * DIN);
  transpose_cast_kernel<<<dim3(DMOD / 32, DIN / 32), 256, 0, stream>>>(out_proj, W2t, DIN, DMOD);

  mfma_gemm<1><<<dim3(24, 64), 256, 0, stream>>>(Xbf, W1t, XI, Z, DMOD, DIN);
  xdbl_kernel<<<128, 256, 0, stream>>>(XI, x_proj, DTLR, BC, CC);
  dt_kernel<<<512, 256, 0, stream>>>(DTLR, dt_proj, dt_b, A_log, BC, XI, DA, H);
  recur_kernel<<<384, 256, 0, stream>>>(DA, H, SLOT_NODE, SLOT_PNODE, LSTART, NLEV);
  ln_kernel<<<ROWS, 256, 0, stream>>>(H, CC, XI, Dp, gamma, beta, Z, YLN);
  mfma_gemm<0><<<dim3(6, 64), 256, 0, stream>>>(YLN, W2t, out, nullptr, DIN, DMOD);
}

// Round 3
// 521.234 us; speedup vs baseline: 2.4746x; 1.2475x over previous
//
#include <hip/hip_runtime.h>
#include <math.h>

// TreeMambaLayer: B=4, N=2048, D_MODEL=768, D_INNER=1536, DT_RANK=48
// Round 3: fix xdbl under-subscription (128 -> 512 blocks, 16 rows/block).
// Big GEMMs stay bf16 MFMA (m97 structure).

#define ROWS 8192
#define DIN 1536
#define DMOD 768
#define NSEQ 2048
#define DTR 48

typedef __bf16 bfrag __attribute__((ext_vector_type(8)));
typedef float f4 __attribute__((ext_vector_type(4)));

__device__ __forceinline__ unsigned short f2bf(float f) {
  unsigned int u = __float_as_uint(f);
  unsigned int r = (u + 0x7fffu + ((u >> 16) & 1u)) >> 16;
  return (unsigned short)r;
}

__device__ __forceinline__ void gld_lds16(const void* g, void* l) {
  __builtin_amdgcn_global_load_lds((const __attribute__((address_space(1))) void*)g,
                                   (__attribute__((address_space(3))) void*)l, 16, 0, 0);
}

// ------------------------------------------------------------- bf16 MFMA GEMM
template <int MODE>
__global__ __launch_bounds__(256) void mfma_gemm(
    const unsigned short* __restrict__ A, const unsigned short* __restrict__ Bt,
    float* __restrict__ C0, float* __restrict__ C1, int K, int ldc) {
  __shared__ unsigned short As[128 * 32];
  __shared__ unsigned short Bs[128 * 32];
  const int tid = threadIdx.x;
  const int w = tid >> 6, l = tid & 63;
  const int quad = l >> 4, l16 = l & 15;
  const int wrow = (w >> 1) * 64, wcol = (w & 1) * 64;
  const int row0 = blockIdx.y * 128, col0 = blockIdx.x * 128;

  f4 acc[4][4];
#pragma unroll
  for (int i = 0; i < 4; i++)
#pragma unroll
    for (int j = 0; j < 4; j++) acc[i][j] = (f4){0.f, 0.f, 0.f, 0.f};

  const int arow = row0 + w * 16 + (l >> 2);
  const int brow = col0 + w * 16 + (l >> 2);
  const int kcol = (l & 3) * 8;

  for (int k0 = 0; k0 < K; k0 += 32) {
#pragma unroll
    for (int r = 0; r < 2; r++) {
      gld_lds16(A + (size_t)(arow + r * 64) * K + k0 + kcol,
                (char*)As + r * 4096 + w * 1024);
      gld_lds16(Bt + (size_t)(brow + r * 64) * K + k0 + kcol,
                (char*)Bs + r * 4096 + w * 1024);
    }
    __syncthreads();
    bfrag af[4], bf[4];
#pragma unroll
    for (int i = 0; i < 4; i++)
      af[i] = *(const bfrag*)(const void*)(As + (wrow + i * 16 + l16) * 32 + quad * 8);
#pragma unroll
    for (int j = 0; j < 4; j++)
      bf[j] = *(const bfrag*)(const void*)(Bs + (wcol + j * 16 + l16) * 32 + quad * 8);
#pragma unroll
    for (int i = 0; i < 4; i++)
#pragma unroll
      for (int j = 0; j < 4; j++)
        acc[i][j] = __builtin_amdgcn_mfma_f32_16x16x32_bf16(af[i], bf[j], acc[i][j], 0, 0, 0);
    __syncthreads();
  }

  if (MODE == 0) {
    const int ccol = col0 + wcol + l16;
#pragma unroll
    for (int i = 0; i < 4; i++) {
      const int rb = row0 + wrow + i * 16 + quad * 4;
#pragma unroll
      for (int j = 0; j < 4; j++)
#pragma unroll
        for (int r = 0; r < 4; r++)
          C0[(size_t)(rb + r) * ldc + ccol + j * 16] = acc[i][j][r];
    }
  } else {
    const bool is_z = (col0 >= DIN);
    float* dst = is_z ? C1 : C0;
    const int cbase = col0 + wcol + l16 - (is_z ? DIN : 0);
#pragma unroll
    for (int i = 0; i < 4; i++) {
      const int rb = row0 + wrow + i * 16 + quad * 4;
#pragma unroll
      for (int j = 0; j < 4; j++)
#pragma unroll
        for (int r = 0; r < 4; r++) {
          float v = acc[i][j][r];
          if (is_z) v = v / (1.f + __expf(-v));
          dst[(size_t)(rb + r) * DIN + cbase + j * 16] = v;
        }
    }
  }
}

// ----------------------------------------------------------------- casts
__global__ __launch_bounds__(256) void cast_bf16_kernel(
    const float* __restrict__ in, unsigned short* __restrict__ out, int n4) {
  const int i = (blockIdx.x * 256 + threadIdx.x) * 4;
  if (i < n4 * 4) {
    const float4 v = *(const float4*)(in + i);
    union { unsigned short h[4]; uint2 u; } p;
    p.h[0] = f2bf(v.x);
    p.h[1] = f2bf(v.y);
    p.h[2] = f2bf(v.z);
    p.h[3] = f2bf(v.w);
    *(uint2*)(out + i) = p.u;
  }
}

// W (K x N) fp32 -> Wt (N x K) bf16
__global__ __launch_bounds__(256) void transpose_cast_kernel(
    const float* __restrict__ W, unsigned short* __restrict__ Wt, int K, int N) {
  __shared__ float t[32][33];
  const int n0 = blockIdx.x * 32, k0 = blockIdx.y * 32;
  const int tx = threadIdx.x & 31, ty = threadIdx.x >> 5;
  for (int i = ty; i < 32; i += 8) t[i][tx] = W[(size_t)(k0 + i) * N + n0 + tx];
  __syncthreads();
  for (int i = ty; i < 32; i += 8)
    Wt[(size_t)(n0 + i) * K + k0 + tx] = f2bf(t[tx][i]);
}

// ------------------------------------------------- x_dbl = x_inner @ x_proj_w
// 512 blocks x 16 rows. thread: row = tid&15, colgroup = tid>>4 (4 cols each).
__global__ __launch_bounds__(256) void xdbl_kernel(
    const float* __restrict__ XI, const float* __restrict__ W,
    float* __restrict__ DTLR, float* __restrict__ BC, float* __restrict__ CC) {
  __shared__ float As[32][17];   // [k][row], pad 17
  __shared__ float Ws[32][68];   // [k][col], pad 68, cols 50..63 zero
  const int tid = threadIdx.x;
  const int row0 = blockIdx.x * 16;
  const int r = tid & 15, cg = tid >> 4;  // cols cg*4 .. cg*4+3

  float acc[4] = {0.f, 0.f, 0.f, 0.f};

  for (int k0 = 0; k0 < DIN; k0 += 32) {
    // stage XI: 16 rows x 32 k = 128 float4 loads (tid < 128)
    if (tid < 128) {
      const int rr = tid >> 3;
      const int c = (tid & 7) << 2;
      const float4 v = *(const float4*)(XI + (size_t)(row0 + rr) * DIN + k0 + c);
      As[c + 0][rr] = v.x;
      As[c + 1][rr] = v.y;
      As[c + 2][rr] = v.z;
      As[c + 3][rr] = v.w;
    }
    // stage W: 32 k x 64 cols (>=50 -> 0), 2048 words / 256 threads = 8 each
#pragma unroll
    for (int h = 0; h < 8; h++) {
      const int idx = tid + h * 256;
      const int kk = idx >> 6, c = idx & 63;
      Ws[kk][c] = (c < 50) ? W[(size_t)(k0 + kk) * 50 + c] : 0.f;
    }
    __syncthreads();
#pragma unroll
    for (int k = 0; k < 32; k++) {
      const float a = As[k][r];
      const float4 wv = *(const float4*)&Ws[k][cg * 4];
      acc[0] = fmaf(a, wv.x, acc[0]);
      acc[1] = fmaf(a, wv.y, acc[1]);
      acc[2] = fmaf(a, wv.z, acc[2]);
      acc[3] = fmaf(a, wv.w, acc[3]);
    }
    __syncthreads();
  }
  const int row = row0 + r;
#pragma unroll
  for (int j = 0; j < 4; j++) {
    const int c = cg * 4 + j;
    if (c < 48)
      DTLR[(size_t)row * DTR + c] = acc[j];
    else if (c == 48)
      BC[row] = acc[j];
    else if (c == 49)
      CC[row] = acc[j];
  }
}

// ----------------------------------- dt/softplus/dA/dBx
__global__ __launch_bounds__(256) void dt_kernel(
    const float* __restrict__ DTLR, const float* __restrict__ Wdt,
    const float* __restrict__ bias, const float* __restrict__ A_log,
    const float* __restrict__ BC, const float* __restrict__ XI,
    float* __restrict__ DA, float* __restrict__ DBX) {
  __shared__ float Lr[16][48];
  __shared__ float Wls[48][256];
  const int tid = threadIdx.x;
  const int row0 = blockIdx.x << 4;
  for (int idx = tid; idx < 16 * 48; idx += 256) {
    const int rr = idx / 48, c = idx % 48;
    Lr[rr][c] = DTLR[(size_t)(row0 + rr) * DTR + c];
  }
  for (int d0 = 0; d0 < DIN; d0 += 256) {
#pragma unroll
    for (int k = 0; k < 48; k++) Wls[k][tid] = Wdt[(size_t)k * DIN + d0 + tid];
    __syncthreads();
    const int d = d0 + tid;
    const float bs = bias[d];
    const float Ad = -__expf(A_log[d]);
    float wv[48];
#pragma unroll
    for (int k = 0; k < 48; k++) wv[k] = Wls[k][tid];
#pragma unroll 2
    for (int rr = 0; rr < 16; rr++) {
      float s = bs;
#pragma unroll
      for (int k = 0; k < 48; k++) s = fmaf(Lr[rr][k], wv[k], s);
      const float sp = fmaxf(s, 0.f) + log1pf(__expf(-fabsf(s)));
      const int row = row0 + rr;
      DA[(size_t)row * DIN + d] = __expf(sp * Ad);
      DBX[(size_t)row * DIN + d] = sp * BC[row] * XI[(size_t)row * DIN + d];
    }
    __syncthreads();
  }
}

// -------------------------------------------------- level schedule (1 block)
__global__ __launch_bounds__(1024) void sched_kernel(
    const int* __restrict__ sidx, const int* __restrict__ spar,
    int* __restrict__ SLOT_NODE, int* __restrict__ SLOT_PNODE,
    int* __restrict__ LSTART, int* __restrict__ NLEV) {
  __shared__ int par[2048], idx[2048], ancA[2048], ancB[2048], rnkA[2048], rnkB[2048];
  __shared__ int dmax;
  const int tid = threadIdx.x;
  for (int i = tid; i < 2048; i += 1024) {
    const int p = spar[i];
    par[i] = p;
    idx[i] = sidx[i];
    ancA[i] = (p < 0) ? -1 : p;
    rnkA[i] = (p < 0) ? 0 : 1;
  }
  if (tid == 0) dmax = 0;
  __syncthreads();
  for (int r = 0; r < 11; r++) {
    int* ca = (r & 1) ? ancB : ancA;
    int* cr = (r & 1) ? rnkB : rnkA;
    int* na = (r & 1) ? ancA : ancB;
    int* nr = (r & 1) ? rnkA : rnkB;
    for (int i = tid; i < 2048; i += 1024) {
      const int a = ca[i], rv = cr[i];
      if (a >= 0) {
        nr[i] = rv + cr[a];
        na[i] = ca[a];
      } else {
        nr[i] = rv;
        na[i] = a;
      }
    }
    __syncthreads();
  }
  for (int i = tid; i < 2048; i += 1024) ancA[i] = 0;
  __syncthreads();
  for (int i = tid; i < 2048; i += 1024) {
    atomicAdd(&ancA[rnkB[i]], 1);
    atomicMax(&dmax, rnkB[i]);
  }
  __syncthreads();
  for (int s = 0; s < 11; s++) {
    const int off = 1 << s;
    int* cur = (s & 1) ? ancB : ancA;
    int* nxt = (s & 1) ? ancA : ancB;
    for (int i = tid; i < 2048; i += 1024) {
      int v = cur[i];
      if (i >= off) v += cur[i - off];
      nxt[i] = v;
    }
    __syncthreads();
  }
  for (int i = tid; i < 2049; i += 1024) {
    const int v = (i == 0) ? 0 : ancB[i - 1];
    LSTART[i] = v;
    if (i < 2048) rnkA[i] = v;
  }
  if (tid == 0) NLEV[0] = dmax + 1;
  __syncthreads();
  for (int i = tid; i < 2048; i += 1024) {
    const int d = rnkB[i];
    const int slot = atomicAdd(&rnkA[d], 1);
    SLOT_NODE[slot] = idx[i];
    const int p = par[i];
    SLOT_PNODE[slot] = (p < 0) ? -1 : idx[p];
  }
}

// ------------------------------------------------------------ tree recurrence
__global__ __launch_bounds__(256) void recur_kernel(
    const float* __restrict__ DA, float* __restrict__ H,
    const int* __restrict__ SLOT_NODE, const int* __restrict__ SLOT_PNODE,
    const int* __restrict__ LSTART, const int* __restrict__ NLEV) {
  const int tid = threadIdx.x;
  const int base_c4 = blockIdx.x * 4;
  const int nlev = NLEV[0];
  const float4* DA4 = (const float4*)DA;
  float4* H4 = (float4*)H;
  for (int L = 0; L < nlev; L++) {
    const int s0 = LSTART[L], s1 = LSTART[L + 1];
    const int items = (s1 - s0) * 4;
    for (int it = tid; it < items; it += 256) {
      const int s = s0 + (it >> 2);
      const int c4 = base_c4 + (it & 3);
      const int node = SLOT_NODE[s];
      const int pn = SLOT_PNODE[s];
      const int b = c4 / 384, d4 = c4 % 384;
      const size_t ib = ((size_t)b * NSEQ + node) * 384 + d4;
      const float4 a = DA4[ib];
      const float4 xv = H4[ib];
      float4 hp = make_float4(0.f, 0.f, 0.f, 0.f);
      if (pn >= 0) hp = H4[((size_t)b * NSEQ + pn) * 384 + d4];
      float4 hv;
      hv.x = fmaf(a.x, hp.x, xv.x);
      hv.y = fmaf(a.y, hp.y, xv.y);
      hv.z = fmaf(a.z, hp.z, xv.z);
      hv.w = fmaf(a.w, hp.w, xv.w);
      H4[ib] = hv;
    }
    __syncthreads();
  }
}

// --------------------------------------------- y, layernorm, z-gate -> bf16
__global__ __launch_bounds__(256) void ln_kernel(
    const float* __restrict__ H, const float* __restrict__ CC,
    const float* __restrict__ XI, const float* __restrict__ Dp,
    const float* __restrict__ gamma, const float* __restrict__ beta,
    const float* __restrict__ Z, unsigned short* __restrict__ YLN) {
  const int row = blockIdx.x;
  const int tid = threadIdx.x;
  const float C = CC[row];
  const float* hrow = H + (size_t)row * DIN;
  const float* xrow = XI + (size_t)row * DIN;
  float y[6];
  float s = 0.f, s2 = 0.f;
#pragma unroll
  for (int i = 0; i < 6; i++) {
    const int d = tid + i * 256;
    const float v = fmaf(hrow[d], C, Dp[d] * xrow[d]);
    y[i] = v;
    s += v;
    s2 = fmaf(v, v, s2);
  }
#pragma unroll
  for (int off = 32; off >= 1; off >>= 1) {
    s += __shfl_down(s, off);
    s2 += __shfl_down(s2, off);
  }
  __shared__ float rs[4], rs2[4];
  const int w = tid >> 6;
  if ((tid & 63) == 0) {
    rs[w] = s;
    rs2[w] = s2;
  }
  __syncthreads();
  const float ts = rs[0] + rs[1] + rs[2] + rs[3];
  const float ts2 = rs2[0] + rs2[1] + rs2[2] + rs2[3];
  const float mu = ts * (1.f / 1536.f);
  const float var = ts2 * (1.f / 1536.f) - mu * mu;
  const float inv = rsqrtf(var + 1e-5f);
  unsigned short* yrow = YLN + (size_t)row * DIN;
  const float* zrow = Z + (size_t)row * DIN;
#pragma unroll
  for (int i = 0; i < 6; i++) {
    const int d = tid + i * 256;
    const float o = (y[i] - mu) * inv * gamma[d] + beta[d];
    yrow[d] = f2bf(o * zrow[d]);
  }
}

// ---------------------------------------------------------------------- launch
extern "C" void kernel_launch(void* const* d_in, const int* in_sizes, int n_in,
                              void* d_out, int out_size, void* d_ws, size_t ws_size,
                              hipStream_t stream) {
  const float* x = (const float*)d_in[0];
  const int* sidx = (const int*)d_in[1];
  const int* spar = (const int*)d_in[2];
  const float* in_proj = (const float*)d_in[3];
  const float* x_proj = (const float*)d_in[4];
  const float* dt_proj = (const float*)d_in[5];
  const float* dt_b = (const float*)d_in[6];
  const float* A_log = (const float*)d_in[7];
  const float* Dp = (const float*)d_in[8];
  const float* gamma = (const float*)d_in[9];
  const float* beta = (const float*)d_in[10];
  const float* out_proj = (const float*)d_in[11];
  float* out = (float*)d_out;

  float* ws = (float*)d_ws;
  const size_t RC = (size_t)ROWS * DIN;  // 12,582,912 floats
  float* XI = ws;                        // x_inner fp32
  float* Z = ws + RC;                    // silu(z) fp32
  float* DA = ws + 2 * RC;               // dA fp32; later reused as YLN (bf16)
  float* H = ws + 3 * RC;                // dBx -> h (in place)
  float* DTLR = ws + 4 * RC;             // 8192*48
  float* BC = DTLR + (size_t)ROWS * DTR;
  float* CC = BC + ROWS;
  int* ipart = (int*)(CC + ROWS);
  int* SLOT_NODE = ipart;
  int* SLOT_PNODE = ipart + 2048;
  int* LSTART = ipart + 4096;
  int* NLEV = ipart + 4096 + 2049;
  unsigned short* Xbf = (unsigned short*)(ipart + 8192);        // 8192x768 bf16
  unsigned short* W1t = Xbf + (size_t)ROWS * DMOD;              // 3072x768 bf16
  unsigned short* W2t = W1t + (size_t)(2 * DIN) * DMOD;         // 768x1536 bf16
  unsigned short* YLN = (unsigned short*)DA;                    // 8192x1536 bf16
  // total ws use: ~223 MB

  sched_kernel<<<1, 1024, 0, stream>>>(sidx, spar, SLOT_NODE, SLOT_PNODE, LSTART, NLEV);
  cast_bf16_kernel<<<(ROWS * DMOD / 4 + 255) / 256, 256, 0, stream>>>(x, Xbf, ROWS * DMOD / 4);
  transpose_cast_kernel<<<dim3(2 * DIN / 32, DMOD / 32), 256, 0, stream>>>(in_proj, W1t, DMOD, 2 * DIN);
  transpose_cast_kernel<<<dim3(DMOD / 32, DIN / 32), 256, 0, stream>>>(out_proj, W2t, DIN, DMOD);

  mfma_gemm<1><<<dim3(24, 64), 256, 0, stream>>>(Xbf, W1t, XI, Z, DMOD, DIN);
  xdbl_kernel<<<512, 256, 0, stream>>>(XI, x_proj, DTLR, BC, CC);
  dt_kernel<<<512, 256, 0, stream>>>(DTLR, dt_proj, dt_b, A_log, BC, XI, DA, H);
  recur_kernel<<<384, 256, 0, stream>>>(DA, H, SLOT_NODE, SLOT_PNODE, LSTART, NLEV);
  ln_kernel<<<ROWS, 256, 0, stream>>>(H, CC, XI, Dp, gamma, beta, Z, YLN);
  mfma_gemm<0><<<dim3(6, 64), 256, 0, stream>>>(YLN, W2t, out, nullptr, DIN, DMOD);
}

// Round 4
// 451.138 us; speedup vs baseline: 2.8591x; 1.1554x over previous
//
#include <hip/hip_runtime.h>
#include <math.h>

// TreeMambaLayer: B=4, N=2048, D_MODEL=768, D_INNER=1536, DT_RANK=48
// Round 4: x_dbl -> split-K bf16 MFMA (8 splits, partial buffers, fp32->bf16
// in-register A conversion); dt_kernel split over d (512x2 grid).

#define ROWS 8192
#define DIN 1536
#define DMOD 768
#define NSEQ 2048
#define DTR 48
#define NSPLIT 8

typedef __bf16 bfrag __attribute__((ext_vector_type(8)));
typedef short s8v __attribute__((ext_vector_type(8)));
typedef float f4 __attribute__((ext_vector_type(4)));

__device__ __forceinline__ unsigned short f2bf(float f) {
  unsigned int u = __float_as_uint(f);
  unsigned int r = (u + 0x7fffu + ((u >> 16) & 1u)) >> 16;
  return (unsigned short)r;
}

__device__ __forceinline__ void gld_lds16(const void* g, void* l) {
  __builtin_amdgcn_global_load_lds((const __attribute__((address_space(1))) void*)g,
                                   (__attribute__((address_space(3))) void*)l, 16, 0, 0);
}

// ------------------------------------------------------------- bf16 MFMA GEMM
template <int MODE>
__global__ __launch_bounds__(256) void mfma_gemm(
    const unsigned short* __restrict__ A, const unsigned short* __restrict__ Bt,
    float* __restrict__ C0, float* __restrict__ C1, int K, int ldc) {
  __shared__ unsigned short As[128 * 32];
  __shared__ unsigned short Bs[128 * 32];
  const int tid = threadIdx.x;
  const int w = tid >> 6, l = tid & 63;
  const int quad = l >> 4, l16 = l & 15;
  const int wrow = (w >> 1) * 64, wcol = (w & 1) * 64;
  const int row0 = blockIdx.y * 128, col0 = blockIdx.x * 128;

  f4 acc[4][4];
#pragma unroll
  for (int i = 0; i < 4; i++)
#pragma unroll
    for (int j = 0; j < 4; j++) acc[i][j] = (f4){0.f, 0.f, 0.f, 0.f};

  const int arow = row0 + w * 16 + (l >> 2);
  const int brow = col0 + w * 16 + (l >> 2);
  const int kcol = (l & 3) * 8;

  for (int k0 = 0; k0 < K; k0 += 32) {
#pragma unroll
    for (int r = 0; r < 2; r++) {
      gld_lds16(A + (size_t)(arow + r * 64) * K + k0 + kcol,
                (char*)As + r * 4096 + w * 1024);
      gld_lds16(Bt + (size_t)(brow + r * 64) * K + k0 + kcol,
                (char*)Bs + r * 4096 + w * 1024);
    }
    __syncthreads();
    bfrag af[4], bf[4];
#pragma unroll
    for (int i = 0; i < 4; i++)
      af[i] = *(const bfrag*)(const void*)(As + (wrow + i * 16 + l16) * 32 + quad * 8);
#pragma unroll
    for (int j = 0; j < 4; j++)
      bf[j] = *(const bfrag*)(const void*)(Bs + (wcol + j * 16 + l16) * 32 + quad * 8);
#pragma unroll
    for (int i = 0; i < 4; i++)
#pragma unroll
      for (int j = 0; j < 4; j++)
        acc[i][j] = __builtin_amdgcn_mfma_f32_16x16x32_bf16(af[i], bf[j], acc[i][j], 0, 0, 0);
    __syncthreads();
  }

  if (MODE == 0) {
    const int ccol = col0 + wcol + l16;
#pragma unroll
    for (int i = 0; i < 4; i++) {
      const int rb = row0 + wrow + i * 16 + quad * 4;
#pragma unroll
      for (int j = 0; j < 4; j++)
#pragma unroll
        for (int r = 0; r < 4; r++)
          C0[(size_t)(rb + r) * ldc + ccol + j * 16] = acc[i][j][r];
    }
  } else {
    const bool is_z = (col0 >= DIN);
    float* dst = is_z ? C1 : C0;
    const int cbase = col0 + wcol + l16 - (is_z ? DIN : 0);
#pragma unroll
    for (int i = 0; i < 4; i++) {
      const int rb = row0 + wrow + i * 16 + quad * 4;
#pragma unroll
      for (int j = 0; j < 4; j++)
#pragma unroll
        for (int r = 0; r < 4; r++) {
          float v = acc[i][j][r];
          if (is_z) v = v / (1.f + __expf(-v));
          dst[(size_t)(rb + r) * DIN + cbase + j * 16] = v;
        }
    }
  }
}

// ----------------------------------------------------------------- casts
__global__ __launch_bounds__(256) void cast_bf16_kernel(
    const float* __restrict__ in, unsigned short* __restrict__ out, int n4) {
  const int i = (blockIdx.x * 256 + threadIdx.x) * 4;
  if (i < n4 * 4) {
    const float4 v = *(const float4*)(in + i);
    union { unsigned short h[4]; uint2 u; } p;
    p.h[0] = f2bf(v.x);
    p.h[1] = f2bf(v.y);
    p.h[2] = f2bf(v.z);
    p.h[3] = f2bf(v.w);
    *(uint2*)(out + i) = p.u;
  }
}

// W (K x N) fp32 -> Wt (N x K) bf16
__global__ __launch_bounds__(256) void transpose_cast_kernel(
    const float* __restrict__ W, unsigned short* __restrict__ Wt, int K, int N) {
  __shared__ float t[32][33];
  const int n0 = blockIdx.x * 32, k0 = blockIdx.y * 32;
  const int tx = threadIdx.x & 31, ty = threadIdx.x >> 5;
  for (int i = ty; i < 32; i += 8) t[i][tx] = W[(size_t)(k0 + i) * N + n0 + tx];
  __syncthreads();
  for (int i = ty; i < 32; i += 8)
    Wt[(size_t)(n0 + i) * K + k0 + tx] = f2bf(t[tx][i]);
}

// x_proj_w (1536 x 50) fp32 -> XPW (64 x 1536) bf16, cols 50..63 zero
__global__ __launch_bounds__(256) void xpw_cast_kernel(
    const float* __restrict__ W, unsigned short* __restrict__ XPW) {
  const int i = blockIdx.x * 256 + threadIdx.x;  // 64*1536
  const int c = i / 1536, k = i % 1536;
  XPW[i] = (c < 50) ? f2bf(W[(size_t)k * 50 + c]) : (unsigned short)0;
}

// ------------------------------------------------- x_dbl: split-K bf16 MFMA
// grid (NSPLIT, 64). Block: 128 rows x 64 cols, K-range split*192..+192.
// A = XI fp32 (converted to bf16 in-register), B = XPW bf16 [64][1536].
// Output: XP[split][row][64] fp32 partials.
__global__ __launch_bounds__(256) void xdbl_mfma(
    const float* __restrict__ XI, const unsigned short* __restrict__ XPW,
    float* __restrict__ XP) {
  __shared__ float AsF[128 * 32];          // layout [kq][half][row]: 16 KB
  __shared__ unsigned short Bs[64 * 32];   // layout [col][k]: 4 KB
  const int tid = threadIdx.x;
  const int w = tid >> 6, l = tid & 63;
  const int quad = l >> 4, l16 = l & 15;
  const int split = blockIdx.x;
  const int row0 = blockIdx.y * 128;
  const int kbase = split * (DIN / NSPLIT);  // 192

  f4 acc[2][4];
#pragma unroll
  for (int i = 0; i < 2; i++)
#pragma unroll
    for (int j = 0; j < 4; j++) acc[i][j] = (f4){0.f, 0.f, 0.f, 0.f};

  // A staging addresses: round r covers kq=r; wave w: half=w>>1, rows (w&1)*64+l
  const int a_row = (w & 1) * 64 + l;
  const int a_koff = (w >> 1) * 4;
  // B staging: col = w*16 + (l>>2), k-off = (l&3)*8
  const int b_col = w * 16 + (l >> 2);
  const int b_koff = (l & 3) * 8;

  for (int c = 0; c < 6; c++) {
    const int k0 = kbase + c * 32;
#pragma unroll
    for (int r = 0; r < 4; r++) {
      gld_lds16(XI + (size_t)(row0 + a_row) * DIN + k0 + r * 8 + a_koff,
                (char*)AsF + r * 4096 + w * 1024);
    }
    gld_lds16(XPW + (size_t)b_col * DIN + k0 + b_koff, (char*)Bs + w * 1024);
    __syncthreads();
    bfrag af[2], bf[4];
#pragma unroll
    for (int i = 0; i < 2; i++) {
      const int m = w * 32 + i * 16 + l16;
      const float4 p0 = *(const float4*)(AsF + quad * 1024 + m * 4);
      const float4 p1 = *(const float4*)(AsF + quad * 1024 + 512 + m * 4);
      union { s8v s; bfrag b; } u;
      u.s[0] = (short)f2bf(p0.x);
      u.s[1] = (short)f2bf(p0.y);
      u.s[2] = (short)f2bf(p0.z);
      u.s[3] = (short)f2bf(p0.w);
      u.s[4] = (short)f2bf(p1.x);
      u.s[5] = (short)f2bf(p1.y);
      u.s[6] = (short)f2bf(p1.z);
      u.s[7] = (short)f2bf(p1.w);
      af[i] = u.b;
    }
#pragma unroll
    for (int j = 0; j < 4; j++)
      bf[j] = *(const bfrag*)(const void*)(Bs + (j * 16 + l16) * 32 + quad * 8);
#pragma unroll
    for (int i = 0; i < 2; i++)
#pragma unroll
      for (int j = 0; j < 4; j++)
        acc[i][j] = __builtin_amdgcn_mfma_f32_16x16x32_bf16(af[i], bf[j], acc[i][j], 0, 0, 0);
    __syncthreads();
  }

  float* dst = XP + (size_t)split * ROWS * 64 + (size_t)row0 * 64;
#pragma unroll
  for (int i = 0; i < 2; i++) {
    const int rb = w * 32 + i * 16 + quad * 4;
#pragma unroll
    for (int j = 0; j < 4; j++) {
      const int col = j * 16 + l16;
#pragma unroll
      for (int r = 0; r < 4; r++) dst[(size_t)(rb + r) * 64 + col] = acc[i][j][r];
    }
  }
}

// ----------------------------------- dt/softplus/dA/dBx (d split over grid.y)
__global__ __launch_bounds__(256) void dt_kernel(
    const float* __restrict__ XP, const float* __restrict__ Wdt,
    const float* __restrict__ bias, const float* __restrict__ A_log,
    const float* __restrict__ XI,
    float* __restrict__ DA, float* __restrict__ DBX) {
  __shared__ float Lr[16][48];
  __shared__ float bcs[16];
  __shared__ float Wls[48][256];
  const int tid = threadIdx.x;
  const int row0 = blockIdx.x << 4;
  const int dbase = blockIdx.y * (DIN / 2);
  for (int idx = tid; idx < 16 * 49; idx += 256) {
    const int rr = idx / 49, c = idx % 49;
    const float* p = XP + (size_t)(row0 + rr) * 64 + c;
    float s = 0.f;
#pragma unroll
    for (int sp = 0; sp < NSPLIT; sp++) s += p[(size_t)sp * ROWS * 64];
    if (c < 48)
      Lr[rr][c] = s;
    else
      bcs[rr] = s;
  }
  for (int d0 = dbase; d0 < dbase + DIN / 2; d0 += 256) {
#pragma unroll
    for (int k = 0; k < 48; k++) Wls[k][tid] = Wdt[(size_t)k * DIN + d0 + tid];
    __syncthreads();
    const int d = d0 + tid;
    const float bs = bias[d];
    const float Ad = -__expf(A_log[d]);
    float wv[48];
#pragma unroll
    for (int k = 0; k < 48; k++) wv[k] = Wls[k][tid];
#pragma unroll 2
    for (int rr = 0; rr < 16; rr++) {
      float s = bs;
#pragma unroll
      for (int k = 0; k < 48; k++) s = fmaf(Lr[rr][k], wv[k], s);
      const float sp = fmaxf(s, 0.f) + log1pf(__expf(-fabsf(s)));
      const int row = row0 + rr;
      DA[(size_t)row * DIN + d] = __expf(sp * Ad);
      DBX[(size_t)row * DIN + d] = sp * bcs[rr] * XI[(size_t)row * DIN + d];
    }
    __syncthreads();
  }
}

// -------------------------------------------------- level schedule (1 block)
__global__ __launch_bounds__(1024) void sched_kernel(
    const int* __restrict__ sidx, const int* __restrict__ spar,
    int* __restrict__ SLOT_NODE, int* __restrict__ SLOT_PNODE,
    int* __restrict__ LSTART, int* __restrict__ NLEV) {
  __shared__ int par[2048], idx[2048], ancA[2048], ancB[2048], rnkA[2048], rnkB[2048];
  __shared__ int dmax;
  const int tid = threadIdx.x;
  for (int i = tid; i < 2048; i += 1024) {
    const int p = spar[i];
    par[i] = p;
    idx[i] = sidx[i];
    ancA[i] = (p < 0) ? -1 : p;
    rnkA[i] = (p < 0) ? 0 : 1;
  }
  if (tid == 0) dmax = 0;
  __syncthreads();
  for (int r = 0; r < 11; r++) {
    int* ca = (r & 1) ? ancB : ancA;
    int* cr = (r & 1) ? rnkB : rnkA;
    int* na = (r & 1) ? ancA : ancB;
    int* nr = (r & 1) ? rnkA : rnkB;
    for (int i = tid; i < 2048; i += 1024) {
      const int a = ca[i], rv = cr[i];
      if (a >= 0) {
        nr[i] = rv + cr[a];
        na[i] = ca[a];
      } else {
        nr[i] = rv;
        na[i] = a;
      }
    }
    __syncthreads();
  }
  for (int i = tid; i < 2048; i += 1024) ancA[i] = 0;
  __syncthreads();
  for (int i = tid; i < 2048; i += 1024) {
    atomicAdd(&ancA[rnkB[i]], 1);
    atomicMax(&dmax, rnkB[i]);
  }
  __syncthreads();
  for (int s = 0; s < 11; s++) {
    const int off = 1 << s;
    int* cur = (s & 1) ? ancB : ancA;
    int* nxt = (s & 1) ? ancA : ancB;
    for (int i = tid; i < 2048; i += 1024) {
      int v = cur[i];
      if (i >= off) v += cur[i - off];
      nxt[i] = v;
    }
    __syncthreads();
  }
  for (int i = tid; i < 2049; i += 1024) {
    const int v = (i == 0) ? 0 : ancB[i - 1];
    LSTART[i] = v;
    if (i < 2048) rnkA[i] = v;
  }
  if (tid == 0) NLEV[0] = dmax + 1;
  __syncthreads();
  for (int i = tid; i < 2048; i += 1024) {
    const int d = rnkB[i];
    const int slot = atomicAdd(&rnkA[d], 1);
    SLOT_NODE[slot] = idx[i];
    const int p = par[i];
    SLOT_PNODE[slot] = (p < 0) ? -1 : idx[p];
  }
}

// ------------------------------------------------------------ tree recurrence
__global__ __launch_bounds__(256) void recur_kernel(
    const float* __restrict__ DA, float* __restrict__ H,
    const int* __restrict__ SLOT_NODE, const int* __restrict__ SLOT_PNODE,
    const int* __restrict__ LSTART, const int* __restrict__ NLEV) {
  const int tid = threadIdx.x;
  const int base_c4 = blockIdx.x * 4;
  const int nlev = NLEV[0];
  const float4* DA4 = (const float4*)DA;
  float4* H4 = (float4*)H;
  for (int L = 0; L < nlev; L++) {
    const int s0 = LSTART[L], s1 = LSTART[L + 1];
    const int items = (s1 - s0) * 4;
    for (int it = tid; it < items; it += 256) {
      const int s = s0 + (it >> 2);
      const int c4 = base_c4 + (it & 3);
      const int node = SLOT_NODE[s];
      const int pn = SLOT_PNODE[s];
      const int b = c4 / 384, d4 = c4 % 384;
      const size_t ib = ((size_t)b * NSEQ + node) * 384 + d4;
      const float4 a = DA4[ib];
      const float4 xv = H4[ib];
      float4 hp = make_float4(0.f, 0.f, 0.f, 0.f);
      if (pn >= 0) hp = H4[((size_t)b * NSEQ + pn) * 384 + d4];
      float4 hv;
      hv.x = fmaf(a.x, hp.x, xv.x);
      hv.y = fmaf(a.y, hp.y, xv.y);
      hv.z = fmaf(a.z, hp.z, xv.z);
      hv.w = fmaf(a.w, hp.w, xv.w);
      H4[ib] = hv;
    }
    __syncthreads();
  }
}

// --------------------------------------------- y, layernorm, z-gate -> bf16
__global__ __launch_bounds__(256) void ln_kernel(
    const float* __restrict__ H, const float* __restrict__ XP,
    const float* __restrict__ XI, const float* __restrict__ Dp,
    const float* __restrict__ gamma, const float* __restrict__ beta,
    const float* __restrict__ Z, unsigned short* __restrict__ YLN) {
  const int row = blockIdx.x;
  const int tid = threadIdx.x;
  float C = 0.f;
  {
    const float* p = XP + (size_t)row * 64 + 49;
#pragma unroll
    for (int sp = 0; sp < NSPLIT; sp++) C += p[(size_t)sp * ROWS * 64];
  }
  const float* hrow = H + (size_t)row * DIN;
  const float* xrow = XI + (size_t)row * DIN;
  float y[6];
  float s = 0.f, s2 = 0.f;
#pragma unroll
  for (int i = 0; i < 6; i++) {
    const int d = tid + i * 256;
    const float v = fmaf(hrow[d], C, Dp[d] * xrow[d]);
    y[i] = v;
    s += v;
    s2 = fmaf(v, v, s2);
  }
#pragma unroll
  for (int off = 32; off >= 1; off >>= 1) {
    s += __shfl_down(s, off);
    s2 += __shfl_down(s2, off);
  }
  __shared__ float rs[4], rs2[4];
  const int w = tid >> 6;
  if ((tid & 63) == 0) {
    rs[w] = s;
    rs2[w] = s2;
  }
  __syncthreads();
  const float ts = rs[0] + rs[1] + rs[2] + rs[3];
  const float ts2 = rs2[0] + rs2[1] + rs2[2] + rs2[3];
  const float mu = ts * (1.f / 1536.f);
  const float var = ts2 * (1.f / 1536.f) - mu * mu;
  const float inv = rsqrtf(var + 1e-5f);
  unsigned short* yrow = YLN + (size_t)row * DIN;
  const float* zrow = Z + (size_t)row * DIN;
#pragma unroll
  for (int i = 0; i < 6; i++) {
    const int d = tid + i * 256;
    const float o = (y[i] - mu) * inv * gamma[d] + beta[d];
    yrow[d] = f2bf(o * zrow[d]);
  }
}

// ---------------------------------------------------------------------- launch
extern "C" void kernel_launch(void* const* d_in, const int* in_sizes, int n_in,
                              void* d_out, int out_size, void* d_ws, size_t ws_size,
                              hipStream_t stream) {
  const float* x = (const float*)d_in[0];
  const int* sidx = (const int*)d_in[1];
  const int* spar = (const int*)d_in[2];
  const float* in_proj = (const float*)d_in[3];
  const float* x_proj = (const float*)d_in[4];
  const float* dt_proj = (const float*)d_in[5];
  const float* dt_b = (const float*)d_in[6];
  const float* A_log = (const float*)d_in[7];
  const float* Dp = (const float*)d_in[8];
  const float* gamma = (const float*)d_in[9];
  const float* beta = (const float*)d_in[10];
  const float* out_proj = (const float*)d_in[11];
  float* out = (float*)d_out;

  float* ws = (float*)d_ws;
  const size_t RC = (size_t)ROWS * DIN;  // 12,582,912 floats
  float* XI = ws;                        // x_inner fp32
  float* Z = ws + RC;                    // silu(z) fp32
  float* DA = ws + 2 * RC;               // dA fp32; later reused as YLN (bf16)
  float* H = ws + 3 * RC;                // dBx -> h (in place)
  int* ipart = (int*)(ws + 4 * RC);
  int* SLOT_NODE = ipart;
  int* SLOT_PNODE = ipart + 2048;
  int* LSTART = ipart + 4096;
  int* NLEV = ipart + 4096 + 2049;
  unsigned short* Xbf = (unsigned short*)(ipart + 8192);   // 8192x768 bf16
  unsigned short* W1t = Xbf + (size_t)ROWS * DMOD;         // 3072x768 bf16
  unsigned short* W2t = W1t + (size_t)(2 * DIN) * DMOD;    // 768x1536 bf16
  unsigned short* XPW = W2t + (size_t)DMOD * DIN;          // 64x1536 bf16
  float* XP = (float*)Xbf;  // 8 x 8192 x 64 fp32 partials; overlays Xbf+W1t
                            // (both dead after mfma_gemm<1>); 16.78MB <= 17.3MB
  unsigned short* YLN = (unsigned short*)DA;               // 8192x1536 bf16

  sched_kernel<<<1, 1024, 0, stream>>>(sidx, spar, SLOT_NODE, SLOT_PNODE, LSTART, NLEV);
  cast_bf16_kernel<<<(ROWS * DMOD / 4 + 255) / 256, 256, 0, stream>>>(x, Xbf, ROWS * DMOD / 4);
  transpose_cast_kernel<<<dim3(2 * DIN / 32, DMOD / 32), 256, 0, stream>>>(in_proj, W1t, DMOD, 2 * DIN);
  transpose_cast_kernel<<<dim3(DMOD / 32, DIN / 32), 256, 0, stream>>>(out_proj, W2t, DIN, DMOD);
  xpw_cast_kernel<<<64 * DIN / 256, 256, 0, stream>>>(x_proj, XPW);

  mfma_gemm<1><<<dim3(24, 64), 256, 0, stream>>>(Xbf, W1t, XI, Z, DMOD, DIN);
  xdbl_mfma<<<dim3(NSPLIT, 64), 256, 0, stream>>>(XI, XPW, XP);
  dt_kernel<<<dim3(512, 2), 256, 0, stream>>>(XP, dt_proj, dt_b, A_log, XI, DA, H);
  recur_kernel<<<384, 256, 0, stream>>>(DA, H, SLOT_NODE, SLOT_PNODE, LSTART, NLEV);
  ln_kernel<<<ROWS, 256, 0, stream>>>(H, XP, XI, Dp, gamma, beta, Z, YLN);
  mfma_gemm<0><<<dim3(6, 64), 256, 0, stream>>>(YLN, W2t, out, nullptr, DIN, DMOD);
}

// Round 5
// 377.863 us; speedup vs baseline: 3.4136x; 1.1939x over previous
//
#include <hip/hip_runtime.h>
#include <math.h>

// TreeMambaLayer: B=4, N=2048, D_MODEL=768, D_INNER=1536, DT_RANK=48
// Round 5: dt -> fused MFMA GEMM (K=64, no k-loop) + bf16 XI/Z everywhere.

#define ROWS 8192
#define DIN 1536
#define DMOD 768
#define NSEQ 2048
#define DTR 48
#define NSPLIT 8

typedef __bf16 bfrag __attribute__((ext_vector_type(8)));
typedef float f4 __attribute__((ext_vector_type(4)));

__device__ __forceinline__ unsigned short f2bf(float f) {
  unsigned int u = __float_as_uint(f);
  unsigned int r = (u + 0x7fffu + ((u >> 16) & 1u)) >> 16;
  return (unsigned short)r;
}
__device__ __forceinline__ float bf2f(unsigned short h) {
  return __uint_as_float(((unsigned int)h) << 16);
}

__device__ __forceinline__ void gld_lds16(const void* g, void* l) {
  __builtin_amdgcn_global_load_lds((const __attribute__((address_space(1))) void*)g,
                                   (__attribute__((address_space(3))) void*)l, 16, 0, 0);
}

// ------------------------------------------------------------- bf16 MFMA GEMM
// MODE 0: C0 = fp32 out (ld = ldc). MODE 1: in_proj -> XI bf16, Z=silu bf16.
template <int MODE>
__global__ __launch_bounds__(256) void mfma_gemm(
    const unsigned short* __restrict__ A, const unsigned short* __restrict__ Bt,
    void* __restrict__ C0v, void* __restrict__ C1v, int K, int ldc) {
  __shared__ unsigned short As[128 * 32];
  __shared__ unsigned short Bs[128 * 32];
  const int tid = threadIdx.x;
  const int w = tid >> 6, l = tid & 63;
  const int quad = l >> 4, l16 = l & 15;
  const int wrow = (w >> 1) * 64, wcol = (w & 1) * 64;
  const int row0 = blockIdx.y * 128, col0 = blockIdx.x * 128;

  f4 acc[4][4];
#pragma unroll
  for (int i = 0; i < 4; i++)
#pragma unroll
    for (int j = 0; j < 4; j++) acc[i][j] = (f4){0.f, 0.f, 0.f, 0.f};

  const int arow = row0 + w * 16 + (l >> 2);
  const int brow = col0 + w * 16 + (l >> 2);
  const int kcol = (l & 3) * 8;

  for (int k0 = 0; k0 < K; k0 += 32) {
#pragma unroll
    for (int r = 0; r < 2; r++) {
      gld_lds16(A + (size_t)(arow + r * 64) * K + k0 + kcol,
                (char*)As + r * 4096 + w * 1024);
      gld_lds16(Bt + (size_t)(brow + r * 64) * K + k0 + kcol,
                (char*)Bs + r * 4096 + w * 1024);
    }
    __syncthreads();
    bfrag af[4], bf[4];
#pragma unroll
    for (int i = 0; i < 4; i++)
      af[i] = *(const bfrag*)(const void*)(As + (wrow + i * 16 + l16) * 32 + quad * 8);
#pragma unroll
    for (int j = 0; j < 4; j++)
      bf[j] = *(const bfrag*)(const void*)(Bs + (wcol + j * 16 + l16) * 32 + quad * 8);
#pragma unroll
    for (int i = 0; i < 4; i++)
#pragma unroll
      for (int j = 0; j < 4; j++)
        acc[i][j] = __builtin_amdgcn_mfma_f32_16x16x32_bf16(af[i], bf[j], acc[i][j], 0, 0, 0);
    __syncthreads();
  }

  if (MODE == 0) {
    float* C0 = (float*)C0v;
    const int ccol = col0 + wcol + l16;
#pragma unroll
    for (int i = 0; i < 4; i++) {
      const int rb = row0 + wrow + i * 16 + quad * 4;
#pragma unroll
      for (int j = 0; j < 4; j++)
#pragma unroll
        for (int r = 0; r < 4; r++)
          C0[(size_t)(rb + r) * ldc + ccol + j * 16] = acc[i][j][r];
    }
  } else {
    const bool is_z = (col0 >= DIN);
    unsigned short* dst = is_z ? (unsigned short*)C1v : (unsigned short*)C0v;
    const int cbase = col0 + wcol + l16 - (is_z ? DIN : 0);
#pragma unroll
    for (int i = 0; i < 4; i++) {
      const int rb = row0 + wrow + i * 16 + quad * 4;
#pragma unroll
      for (int j = 0; j < 4; j++)
#pragma unroll
        for (int r = 0; r < 4; r++) {
          float v = acc[i][j][r];
          if (is_z) v = v / (1.f + __expf(-v));
          dst[(size_t)(rb + r) * DIN + cbase + j * 16] = f2bf(v);
        }
    }
  }
}

// ----------------------------------------------------------------- casts
__global__ __launch_bounds__(256) void cast_bf16_kernel(
    const float* __restrict__ in, unsigned short* __restrict__ out, int n4) {
  const int i = (blockIdx.x * 256 + threadIdx.x) * 4;
  if (i < n4 * 4) {
    const float4 v = *(const float4*)(in + i);
    union { unsigned short h[4]; uint2 u; } p;
    p.h[0] = f2bf(v.x);
    p.h[1] = f2bf(v.y);
    p.h[2] = f2bf(v.z);
    p.h[3] = f2bf(v.w);
    *(uint2*)(out + i) = p.u;
  }
}

// W (K x N) fp32 -> Wt (N x K) bf16
__global__ __launch_bounds__(256) void transpose_cast_kernel(
    const float* __restrict__ W, unsigned short* __restrict__ Wt, int K, int N) {
  __shared__ float t[32][33];
  const int n0 = blockIdx.x * 32, k0 = blockIdx.y * 32;
  const int tx = threadIdx.x & 31, ty = threadIdx.x >> 5;
  for (int i = ty; i < 32; i += 8) t[i][tx] = W[(size_t)(k0 + i) * N + n0 + tx];
  __syncthreads();
  for (int i = ty; i < 32; i += 8)
    Wt[(size_t)(n0 + i) * K + k0 + tx] = f2bf(t[tx][i]);
}

// x_proj_w (1536 x 50) fp32 -> XPW (64 x 1536) bf16, cols 50..63 zero
__global__ __launch_bounds__(256) void xpw_cast_kernel(
    const float* __restrict__ W, unsigned short* __restrict__ XPW) {
  const int i = blockIdx.x * 256 + threadIdx.x;  // 64*1536
  const int c = i / 1536, k = i % 1536;
  XPW[i] = (c < 50) ? f2bf(W[(size_t)k * 50 + c]) : (unsigned short)0;
}

// dt_proj_w (48 x 1536) fp32 -> DTWb (1536 x 64) bf16, k 48..63 zero
__global__ __launch_bounds__(256) void dtw_cast_kernel(
    const float* __restrict__ W, unsigned short* __restrict__ DTWb) {
  const int i = blockIdx.x * 256 + threadIdx.x;  // 1536*64
  const int d = i >> 6, k = i & 63;
  DTWb[i] = (k < 48) ? f2bf(W[(size_t)k * DIN + d]) : (unsigned short)0;
}

// ------------------------------------------------- x_dbl: split-K bf16 MFMA
// grid (NSPLIT, 64). Block: 128 rows x 64 cols, K-range split*192..+192.
__global__ __launch_bounds__(256) void xdbl_mfma(
    const unsigned short* __restrict__ XI, const unsigned short* __restrict__ XPW,
    float* __restrict__ XP) {
  __shared__ unsigned short As[128 * 32];
  __shared__ unsigned short Bs[64 * 32];
  const int tid = threadIdx.x;
  const int w = tid >> 6, l = tid & 63;
  const int quad = l >> 4, l16 = l & 15;
  const int split = blockIdx.x;
  const int row0 = blockIdx.y * 128;
  const int kbase = split * (DIN / NSPLIT);  // 192

  f4 acc[2][4];
#pragma unroll
  for (int i = 0; i < 2; i++)
#pragma unroll
    for (int j = 0; j < 4; j++) acc[i][j] = (f4){0.f, 0.f, 0.f, 0.f};

  const int srow = w * 16 + (l >> 2);
  const int kcol = (l & 3) * 8;

  for (int c = 0; c < 6; c++) {
    const int k0 = kbase + c * 32;
#pragma unroll
    for (int r = 0; r < 2; r++) {
      gld_lds16(XI + (size_t)(row0 + srow + r * 64) * DIN + k0 + kcol,
                (char*)As + r * 4096 + w * 1024);
    }
    gld_lds16(XPW + (size_t)srow * DIN + k0 + kcol, (char*)Bs + w * 1024);
    __syncthreads();
    bfrag af[2], bf[4];
#pragma unroll
    for (int i = 0; i < 2; i++)
      af[i] = *(const bfrag*)(const void*)(As + (w * 32 + i * 16 + l16) * 32 + quad * 8);
#pragma unroll
    for (int j = 0; j < 4; j++)
      bf[j] = *(const bfrag*)(const void*)(Bs + (j * 16 + l16) * 32 + quad * 8);
#pragma unroll
    for (int i = 0; i < 2; i++)
#pragma unroll
      for (int j = 0; j < 4; j++)
        acc[i][j] = __builtin_amdgcn_mfma_f32_16x16x32_bf16(af[i], bf[j], acc[i][j], 0, 0, 0);
    __syncthreads();
  }

  float* dst = XP + (size_t)split * ROWS * 64 + (size_t)row0 * 64;
#pragma unroll
  for (int i = 0; i < 2; i++) {
    const int rb = w * 32 + i * 16 + quad * 4;
#pragma unroll
    for (int j = 0; j < 4; j++) {
      const int col = j * 16 + l16;
#pragma unroll
      for (int r = 0; r < 4; r++) dst[(size_t)(rb + r) * 64 + col] = acc[i][j][r];
    }
  }
}

// -------------------------- reduce XP partials -> DTLRb bf16 + BC/CC fp32
__global__ __launch_bounds__(256) void xp_reduce(
    const float* __restrict__ XP, unsigned short* __restrict__ DTLRb,
    float* __restrict__ BCv, float* __restrict__ CCv) {
  const int i = blockIdx.x * 256 + threadIdx.x;  // 8192*16
  const int row = i >> 4, c4 = (i & 15) * 4;
  const float* p = XP + (size_t)row * 64 + c4;
  float4 s = make_float4(0.f, 0.f, 0.f, 0.f);
#pragma unroll
  for (int sp = 0; sp < NSPLIT; sp++) {
    const float4 v = *(const float4*)(p + (size_t)sp * ROWS * 64);
    s.x += v.x;
    s.y += v.y;
    s.z += v.z;
    s.w += v.w;
  }
  if (c4 == 48) {
    BCv[row] = s.x;
    CCv[row] = s.y;
  }
  union { unsigned short h[4]; uint2 u; } pk;
  pk.h[0] = f2bf(s.x);
  pk.h[1] = f2bf(s.y);
  pk.h[2] = f2bf(s.z);
  pk.h[3] = f2bf(s.w);
  *(uint2*)(DTLRb + (size_t)row * 64 + c4) = pk.u;
}

// ------------------- dt GEMM (K=64, no k-loop) + softplus/dA/dBx epilogue
// grid (12, 64). DA[row][d] = exp(dt * -exp(A_log[d])); H[row][d] = dt*BC*xi.
__global__ __launch_bounds__(256) void dt_gemm(
    const unsigned short* __restrict__ DTLRb, const unsigned short* __restrict__ DTWb,
    const float* __restrict__ bias, const float* __restrict__ A_log,
    const float* __restrict__ BCv, const unsigned short* __restrict__ XI,
    float* __restrict__ DA, float* __restrict__ H) {
  __shared__ unsigned short As[2][128 * 32];
  __shared__ unsigned short Bs[2][128 * 32];
  __shared__ float bcs[128];
  const int tid = threadIdx.x;
  const int w = tid >> 6, l = tid & 63;
  const int quad = l >> 4, l16 = l & 15;
  const int wrow = (w >> 1) * 64, wcol = (w & 1) * 64;
  const int row0 = blockIdx.y * 128, col0 = blockIdx.x * 128;
  const int srow = w * 16 + (l >> 2);
  const int koff = (l & 3) * 8;

#pragma unroll
  for (int c = 0; c < 2; c++)
#pragma unroll
    for (int r = 0; r < 2; r++) {
      gld_lds16(DTLRb + (size_t)(row0 + srow + r * 64) * 64 + c * 32 + koff,
                (char*)As[c] + r * 4096 + w * 1024);
      gld_lds16(DTWb + (size_t)(col0 + srow + r * 64) * 64 + c * 32 + koff,
                (char*)Bs[c] + r * 4096 + w * 1024);
    }
  if (tid < 128) bcs[tid] = BCv[row0 + tid];
  __syncthreads();

  f4 acc[4][4];
#pragma unroll
  for (int i = 0; i < 4; i++)
#pragma unroll
    for (int j = 0; j < 4; j++) acc[i][j] = (f4){0.f, 0.f, 0.f, 0.f};

#pragma unroll
  for (int c = 0; c < 2; c++) {
    bfrag af[4], bf[4];
#pragma unroll
    for (int i = 0; i < 4; i++)
      af[i] = *(const bfrag*)(const void*)(As[c] + (wrow + i * 16 + l16) * 32 + quad * 8);
#pragma unroll
    for (int j = 0; j < 4; j++)
      bf[j] = *(const bfrag*)(const void*)(Bs[c] + (wcol + j * 16 + l16) * 32 + quad * 8);
#pragma unroll
    for (int i = 0; i < 4; i++)
#pragma unroll
      for (int j = 0; j < 4; j++)
        acc[i][j] = __builtin_amdgcn_mfma_f32_16x16x32_bf16(af[i], bf[j], acc[i][j], 0, 0, 0);
  }

  float bj[4], aj[4];
#pragma unroll
  for (int j = 0; j < 4; j++) {
    const int d = col0 + wcol + j * 16 + l16;
    bj[j] = bias[d];
    aj[j] = -__expf(A_log[d]);
  }
#pragma unroll
  for (int i = 0; i < 4; i++) {
#pragma unroll
    for (int r = 0; r < 4; r++) {
      const int row_l = wrow + i * 16 + quad * 4 + r;
      const int row = row0 + row_l;
      const float bc = bcs[row_l];
#pragma unroll
      for (int j = 0; j < 4; j++) {
        const int d = col0 + wcol + j * 16 + l16;
        const float s = acc[i][j][r] + bj[j];
        const float sp = fmaxf(s, 0.f) + log1pf(__expf(-fabsf(s)));
        DA[(size_t)row * DIN + d] = __expf(sp * aj[j]);
        const float xi = bf2f(XI[(size_t)row * DIN + d]);
        H[(size_t)row * DIN + d] = sp * bc * xi;
      }
    }
  }
}

// -------------------------------------------------- level schedule (1 block)
__global__ __launch_bounds__(1024) void sched_kernel(
    const int* __restrict__ sidx, const int* __restrict__ spar,
    int* __restrict__ SLOT_NODE, int* __restrict__ SLOT_PNODE,
    int* __restrict__ LSTART, int* __restrict__ NLEV) {
  __shared__ int par[2048], idx[2048], ancA[2048], ancB[2048], rnkA[2048], rnkB[2048];
  __shared__ int dmax;
  const int tid = threadIdx.x;
  for (int i = tid; i < 2048; i += 1024) {
    const int p = spar[i];
    par[i] = p;
    idx[i] = sidx[i];
    ancA[i] = (p < 0) ? -1 : p;
    rnkA[i] = (p < 0) ? 0 : 1;
  }
  if (tid == 0) dmax = 0;
  __syncthreads();
  for (int r = 0; r < 11; r++) {
    int* ca = (r & 1) ? ancB : ancA;
    int* cr = (r & 1) ? rnkB : rnkA;
    int* na = (r & 1) ? ancA : ancB;
    int* nr = (r & 1) ? rnkA : rnkB;
    for (int i = tid; i < 2048; i += 1024) {
      const int a = ca[i], rv = cr[i];
      if (a >= 0) {
        nr[i] = rv + cr[a];
        na[i] = ca[a];
      } else {
        nr[i] = rv;
        na[i] = a;
      }
    }
    __syncthreads();
  }
  for (int i = tid; i < 2048; i += 1024) ancA[i] = 0;
  __syncthreads();
  for (int i = tid; i < 2048; i += 1024) {
    atomicAdd(&ancA[rnkB[i]], 1);
    atomicMax(&dmax, rnkB[i]);
  }
  __syncthreads();
  for (int s = 0; s < 11; s++) {
    const int off = 1 << s;
    int* cur = (s & 1) ? ancB : ancA;
    int* nxt = (s & 1) ? ancA : ancB;
    for (int i = tid; i < 2048; i += 1024) {
      int v = cur[i];
      if (i >= off) v += cur[i - off];
      nxt[i] = v;
    }
    __syncthreads();
  }
  for (int i = tid; i < 2049; i += 1024) {
    const int v = (i == 0) ? 0 : ancB[i - 1];
    LSTART[i] = v;
    if (i < 2048) rnkA[i] = v;
  }
  if (tid == 0) NLEV[0] = dmax + 1;
  __syncthreads();
  for (int i = tid; i < 2048; i += 1024) {
    const int d = rnkB[i];
    const int slot = atomicAdd(&rnkA[d], 1);
    SLOT_NODE[slot] = idx[i];
    const int p = par[i];
    SLOT_PNODE[slot] = (p < 0) ? -1 : idx[p];
  }
}

// ------------------------------------------------------------ tree recurrence
__global__ __launch_bounds__(256) void recur_kernel(
    const float* __restrict__ DA, float* __restrict__ H,
    const int* __restrict__ SLOT_NODE, const int* __restrict__ SLOT_PNODE,
    const int* __restrict__ LSTART, const int* __restrict__ NLEV) {
  const int tid = threadIdx.x;
  const int base_c4 = blockIdx.x * 4;
  const int nlev = NLEV[0];
  const float4* DA4 = (const float4*)DA;
  float4* H4 = (float4*)H;
  for (int L = 0; L < nlev; L++) {
    const int s0 = LSTART[L], s1 = LSTART[L + 1];
    const int items = (s1 - s0) * 4;
    for (int it = tid; it < items; it += 256) {
      const int s = s0 + (it >> 2);
      const int c4 = base_c4 + (it & 3);
      const int node = SLOT_NODE[s];
      const int pn = SLOT_PNODE[s];
      const int b = c4 / 384, d4 = c4 % 384;
      const size_t ib = ((size_t)b * NSEQ + node) * 384 + d4;
      const float4 a = DA4[ib];
      const float4 xv = H4[ib];
      float4 hp = make_float4(0.f, 0.f, 0.f, 0.f);
      if (pn >= 0) hp = H4[((size_t)b * NSEQ + pn) * 384 + d4];
      float4 hv;
      hv.x = fmaf(a.x, hp.x, xv.x);
      hv.y = fmaf(a.y, hp.y, xv.y);
      hv.z = fmaf(a.z, hp.z, xv.z);
      hv.w = fmaf(a.w, hp.w, xv.w);
      H4[ib] = hv;
    }
    __syncthreads();
  }
}

// --------------------------------------------- y, layernorm, z-gate -> bf16
__global__ __launch_bounds__(256) void ln_kernel(
    const float* __restrict__ H, const float* __restrict__ CCv,
    const unsigned short* __restrict__ XI, const float* __restrict__ Dp,
    const float* __restrict__ gamma, const float* __restrict__ beta,
    const unsigned short* __restrict__ Z, unsigned short* __restrict__ YLN) {
  const int row = blockIdx.x;
  const int tid = threadIdx.x;
  const float C = CCv[row];
  const float* hrow = H + (size_t)row * DIN;
  const unsigned short* xrow = XI + (size_t)row * DIN;
  float y[6];
  float s = 0.f, s2 = 0.f;
#pragma unroll
  for (int i = 0; i < 6; i++) {
    const int d = tid + i * 256;
    const float v = fmaf(hrow[d], C, Dp[d] * bf2f(xrow[d]));
    y[i] = v;
    s += v;
    s2 = fmaf(v, v, s2);
  }
#pragma unroll
  for (int off = 32; off >= 1; off >>= 1) {
    s += __shfl_down(s, off);
    s2 += __shfl_down(s2, off);
  }
  __shared__ float rs[4], rs2[4];
  const int w = tid >> 6;
  if ((tid & 63) == 0) {
    rs[w] = s;
    rs2[w] = s2;
  }
  __syncthreads();
  const float ts = rs[0] + rs[1] + rs[2] + rs[3];
  const float ts2 = rs2[0] + rs2[1] + rs2[2] + rs2[3];
  const float mu = ts * (1.f / 1536.f);
  const float var = ts2 * (1.f / 1536.f) - mu * mu;
  const float inv = rsqrtf(var + 1e-5f);
  unsigned short* yrow = YLN + (size_t)row * DIN;
  const unsigned short* zrow = Z + (size_t)row * DIN;
#pragma unroll
  for (int i = 0; i < 6; i++) {
    const int d = tid + i * 256;
    const float o = (y[i] - mu) * inv * gamma[d] + beta[d];
    yrow[d] = f2bf(o * bf2f(zrow[d]));
  }
}

// ---------------------------------------------------------------------- launch
extern "C" void kernel_launch(void* const* d_in, const int* in_sizes, int n_in,
                              void* d_out, int out_size, void* d_ws, size_t ws_size,
                              hipStream_t stream) {
  const float* x = (const float*)d_in[0];
  const int* sidx = (const int*)d_in[1];
  const int* spar = (const int*)d_in[2];
  const float* in_proj = (const float*)d_in[3];
  const float* x_proj = (const float*)d_in[4];
  const float* dt_proj = (const float*)d_in[5];
  const float* dt_b = (const float*)d_in[6];
  const float* A_log = (const float*)d_in[7];
  const float* Dp = (const float*)d_in[8];
  const float* gamma = (const float*)d_in[9];
  const float* beta = (const float*)d_in[10];
  const float* out_proj = (const float*)d_in[11];
  float* out = (float*)d_out;

  char* p = (char*)d_ws;
  const size_t RC = (size_t)ROWS * DIN;
  unsigned short* XI = (unsigned short*)p;  p += RC * 2;               // 25.2 MB
  unsigned short* Z = (unsigned short*)p;   p += RC * 2;               // 25.2 MB
  float* DA = (float*)p;                    p += RC * 4;               // 50.3 MB
  float* H = (float*)p;                     p += RC * 4;               // 50.3 MB
  float* XP = (float*)p;                    p += (size_t)NSPLIT * ROWS * 64 * 4;  // 16.8 MB
  unsigned short* DTLRb = (unsigned short*)p; p += (size_t)ROWS * 64 * 2;  // 1 MB
  float* BCv = (float*)p;                   p += ROWS * 4;
  float* CCv = (float*)p;                   p += ROWS * 4;
  unsigned short* Xbf = (unsigned short*)p; p += (size_t)ROWS * DMOD * 2;        // 12.6 MB
  unsigned short* W1t = (unsigned short*)p; p += (size_t)2 * DIN * DMOD * 2;     // 4.7 MB
  unsigned short* W2t = (unsigned short*)p; p += (size_t)DMOD * DIN * 2;         // 2.4 MB
  unsigned short* XPW = (unsigned short*)p; p += (size_t)64 * DIN * 2;
  unsigned short* DTWb = (unsigned short*)p; p += (size_t)DIN * 64 * 2;
  int* ipart = (int*)p;
  int* SLOT_NODE = ipart;
  int* SLOT_PNODE = ipart + 2048;
  int* LSTART = ipart + 4096;
  int* NLEV = ipart + 4096 + 2049;
  unsigned short* YLN = (unsigned short*)DA;  // DA dead after recur

  sched_kernel<<<1, 1024, 0, stream>>>(sidx, spar, SLOT_NODE, SLOT_PNODE, LSTART, NLEV);
  cast_bf16_kernel<<<(ROWS * DMOD / 4 + 255) / 256, 256, 0, stream>>>(x, Xbf, ROWS * DMOD / 4);
  transpose_cast_kernel<<<dim3(2 * DIN / 32, DMOD / 32), 256, 0, stream>>>(in_proj, W1t, DMOD, 2 * DIN);
  transpose_cast_kernel<<<dim3(DMOD / 32, DIN / 32), 256, 0, stream>>>(out_proj, W2t, DIN, DMOD);
  xpw_cast_kernel<<<64 * DIN / 256, 256, 0, stream>>>(x_proj, XPW);
  dtw_cast_kernel<<<DIN * 64 / 256, 256, 0, stream>>>(dt_proj, DTWb);

  mfma_gemm<1><<<dim3(24, 64), 256, 0, stream>>>(Xbf, W1t, XI, Z, DMOD, DIN);
  xdbl_mfma<<<dim3(NSPLIT, 64), 256, 0, stream>>>(XI, XPW, XP);
  xp_reduce<<<ROWS * 16 / 256, 256, 0, stream>>>(XP, DTLRb, BCv, CCv);
  dt_gemm<<<dim3(12, 64), 256, 0, stream>>>(DTLRb, DTWb, dt_b, A_log, BCv, XI, DA, H);
  recur_kernel<<<384, 256, 0, stream>>>(DA, H, SLOT_NODE, SLOT_PNODE, LSTART, NLEV);
  ln_kernel<<<ROWS, 256, 0, stream>>>(H, CCv, XI, Dp, gamma, beta, Z, YLN);
  mfma_gemm<0><<<dim3(6, 64), 256, 0, stream>>>(YLN, W2t, out, nullptr, DIN, DMOD);
}

// Round 6
// 346.559 us; speedup vs baseline: 3.7219x; 1.0903x over previous
//
#include <hip/hip_runtime.h>
#include <math.h>

// TreeMambaLayer: B=4, N=2048, D_MODEL=768, D_INNER=1536, DT_RANK=48
// Round 6: dt_gemm emits only dt (bf16, 25MB); dA/dBx fused into recur's
// level sweep (reads dt+xi bf16, writes h fp32). DA buffer eliminated.

#define ROWS 8192
#define DIN 1536
#define DMOD 768
#define NSEQ 2048
#define DTR 48
#define NSPLIT 8

typedef __bf16 bfrag __attribute__((ext_vector_type(8)));
typedef float f4 __attribute__((ext_vector_type(4)));

__device__ __forceinline__ unsigned short f2bf(float f) {
  unsigned int u = __float_as_uint(f);
  unsigned int r = (u + 0x7fffu + ((u >> 16) & 1u)) >> 16;
  return (unsigned short)r;
}
__device__ __forceinline__ float bf2f(unsigned short h) {
  return __uint_as_float(((unsigned int)h) << 16);
}

__device__ __forceinline__ void gld_lds16(const void* g, void* l) {
  __builtin_amdgcn_global_load_lds((const __attribute__((address_space(1))) void*)g,
                                   (__attribute__((address_space(3))) void*)l, 16, 0, 0);
}

// ------------------------------------------------------------- bf16 MFMA GEMM
// MODE 0: C0 = fp32 out (ld = ldc). MODE 1: in_proj -> XI bf16, Z=silu bf16.
template <int MODE>
__global__ __launch_bounds__(256) void mfma_gemm(
    const unsigned short* __restrict__ A, const unsigned short* __restrict__ Bt,
    void* __restrict__ C0v, void* __restrict__ C1v, int K, int ldc) {
  __shared__ unsigned short As[128 * 32];
  __shared__ unsigned short Bs[128 * 32];
  const int tid = threadIdx.x;
  const int w = tid >> 6, l = tid & 63;
  const int quad = l >> 4, l16 = l & 15;
  const int wrow = (w >> 1) * 64, wcol = (w & 1) * 64;
  const int row0 = blockIdx.y * 128, col0 = blockIdx.x * 128;

  f4 acc[4][4];
#pragma unroll
  for (int i = 0; i < 4; i++)
#pragma unroll
    for (int j = 0; j < 4; j++) acc[i][j] = (f4){0.f, 0.f, 0.f, 0.f};

  const int arow = row0 + w * 16 + (l >> 2);
  const int brow = col0 + w * 16 + (l >> 2);
  const int kcol = (l & 3) * 8;

  for (int k0 = 0; k0 < K; k0 += 32) {
#pragma unroll
    for (int r = 0; r < 2; r++) {
      gld_lds16(A + (size_t)(arow + r * 64) * K + k0 + kcol,
                (char*)As + r * 4096 + w * 1024);
      gld_lds16(Bt + (size_t)(brow + r * 64) * K + k0 + kcol,
                (char*)Bs + r * 4096 + w * 1024);
    }
    __syncthreads();
    bfrag af[4], bf[4];
#pragma unroll
    for (int i = 0; i < 4; i++)
      af[i] = *(const bfrag*)(const void*)(As + (wrow + i * 16 + l16) * 32 + quad * 8);
#pragma unroll
    for (int j = 0; j < 4; j++)
      bf[j] = *(const bfrag*)(const void*)(Bs + (wcol + j * 16 + l16) * 32 + quad * 8);
#pragma unroll
    for (int i = 0; i < 4; i++)
#pragma unroll
      for (int j = 0; j < 4; j++)
        acc[i][j] = __builtin_amdgcn_mfma_f32_16x16x32_bf16(af[i], bf[j], acc[i][j], 0, 0, 0);
    __syncthreads();
  }

  if (MODE == 0) {
    float* C0 = (float*)C0v;
    const int ccol = col0 + wcol + l16;
#pragma unroll
    for (int i = 0; i < 4; i++) {
      const int rb = row0 + wrow + i * 16 + quad * 4;
#pragma unroll
      for (int j = 0; j < 4; j++)
#pragma unroll
        for (int r = 0; r < 4; r++)
          C0[(size_t)(rb + r) * ldc + ccol + j * 16] = acc[i][j][r];
    }
  } else {
    const bool is_z = (col0 >= DIN);
    unsigned short* dst = is_z ? (unsigned short*)C1v : (unsigned short*)C0v;
    const int cbase = col0 + wcol + l16 - (is_z ? DIN : 0);
#pragma unroll
    for (int i = 0; i < 4; i++) {
      const int rb = row0 + wrow + i * 16 + quad * 4;
#pragma unroll
      for (int j = 0; j < 4; j++)
#pragma unroll
        for (int r = 0; r < 4; r++) {
          float v = acc[i][j][r];
          if (is_z) v = v / (1.f + __expf(-v));
          dst[(size_t)(rb + r) * DIN + cbase + j * 16] = f2bf(v);
        }
    }
  }
}

// ----------------------------------------------------------------- casts
__global__ __launch_bounds__(256) void cast_bf16_kernel(
    const float* __restrict__ in, unsigned short* __restrict__ out, int n4) {
  const int i = (blockIdx.x * 256 + threadIdx.x) * 4;
  if (i < n4 * 4) {
    const float4 v = *(const float4*)(in + i);
    union { unsigned short h[4]; uint2 u; } p;
    p.h[0] = f2bf(v.x);
    p.h[1] = f2bf(v.y);
    p.h[2] = f2bf(v.z);
    p.h[3] = f2bf(v.w);
    *(uint2*)(out + i) = p.u;
  }
}

// W (K x N) fp32 -> Wt (N x K) bf16
__global__ __launch_bounds__(256) void transpose_cast_kernel(
    const float* __restrict__ W, unsigned short* __restrict__ Wt, int K, int N) {
  __shared__ float t[32][33];
  const int n0 = blockIdx.x * 32, k0 = blockIdx.y * 32;
  const int tx = threadIdx.x & 31, ty = threadIdx.x >> 5;
  for (int i = ty; i < 32; i += 8) t[i][tx] = W[(size_t)(k0 + i) * N + n0 + tx];
  __syncthreads();
  for (int i = ty; i < 32; i += 8)
    Wt[(size_t)(n0 + i) * K + k0 + tx] = f2bf(t[tx][i]);
}

// x_proj_w (1536 x 50) fp32 -> XPW (64 x 1536) bf16, cols 50..63 zero
__global__ __launch_bounds__(256) void xpw_cast_kernel(
    const float* __restrict__ W, unsigned short* __restrict__ XPW) {
  const int i = blockIdx.x * 256 + threadIdx.x;  // 64*1536
  const int c = i / 1536, k = i % 1536;
  XPW[i] = (c < 50) ? f2bf(W[(size_t)k * 50 + c]) : (unsigned short)0;
}

// dt_proj_w (48 x 1536) fp32 -> DTWb (1536 x 64) bf16, k 48..63 zero
__global__ __launch_bounds__(256) void dtw_cast_kernel(
    const float* __restrict__ W, unsigned short* __restrict__ DTWb) {
  const int i = blockIdx.x * 256 + threadIdx.x;  // 1536*64
  const int d = i >> 6, k = i & 63;
  DTWb[i] = (k < 48) ? f2bf(W[(size_t)k * DIN + d]) : (unsigned short)0;
}

// negA[d] = -exp(A_log[d])
__global__ __launch_bounds__(256) void negexpa_kernel(
    const float* __restrict__ A_log, float* __restrict__ negA) {
  const int i = blockIdx.x * 256 + threadIdx.x;
  if (i < DIN) negA[i] = -__expf(A_log[i]);
}

// ------------------------------------------------- x_dbl: split-K bf16 MFMA
__global__ __launch_bounds__(256) void xdbl_mfma(
    const unsigned short* __restrict__ XI, const unsigned short* __restrict__ XPW,
    float* __restrict__ XP) {
  __shared__ unsigned short As[128 * 32];
  __shared__ unsigned short Bs[64 * 32];
  const int tid = threadIdx.x;
  const int w = tid >> 6, l = tid & 63;
  const int quad = l >> 4, l16 = l & 15;
  const int split = blockIdx.x;
  const int row0 = blockIdx.y * 128;
  const int kbase = split * (DIN / NSPLIT);  // 192

  f4 acc[2][4];
#pragma unroll
  for (int i = 0; i < 2; i++)
#pragma unroll
    for (int j = 0; j < 4; j++) acc[i][j] = (f4){0.f, 0.f, 0.f, 0.f};

  const int srow = w * 16 + (l >> 2);
  const int kcol = (l & 3) * 8;

  for (int c = 0; c < 6; c++) {
    const int k0 = kbase + c * 32;
#pragma unroll
    for (int r = 0; r < 2; r++) {
      gld_lds16(XI + (size_t)(row0 + srow + r * 64) * DIN + k0 + kcol,
                (char*)As + r * 4096 + w * 1024);
    }
    gld_lds16(XPW + (size_t)srow * DIN + k0 + kcol, (char*)Bs + w * 1024);
    __syncthreads();
    bfrag af[2], bf[4];
#pragma unroll
    for (int i = 0; i < 2; i++)
      af[i] = *(const bfrag*)(const void*)(As + (w * 32 + i * 16 + l16) * 32 + quad * 8);
#pragma unroll
    for (int j = 0; j < 4; j++)
      bf[j] = *(const bfrag*)(const void*)(Bs + (j * 16 + l16) * 32 + quad * 8);
#pragma unroll
    for (int i = 0; i < 2; i++)
#pragma unroll
      for (int j = 0; j < 4; j++)
        acc[i][j] = __builtin_amdgcn_mfma_f32_16x16x32_bf16(af[i], bf[j], acc[i][j], 0, 0, 0);
    __syncthreads();
  }

  float* dst = XP + (size_t)split * ROWS * 64 + (size_t)row0 * 64;
#pragma unroll
  for (int i = 0; i < 2; i++) {
    const int rb = w * 32 + i * 16 + quad * 4;
#pragma unroll
    for (int j = 0; j < 4; j++) {
      const int col = j * 16 + l16;
#pragma unroll
      for (int r = 0; r < 4; r++) dst[(size_t)(rb + r) * 64 + col] = acc[i][j][r];
    }
  }
}

// -------------------------- reduce XP partials -> DTLRb bf16 + BC/CC fp32
__global__ __launch_bounds__(256) void xp_reduce(
    const float* __restrict__ XP, unsigned short* __restrict__ DTLRb,
    float* __restrict__ BCv, float* __restrict__ CCv) {
  const int i = blockIdx.x * 256 + threadIdx.x;  // 8192*16
  const int row = i >> 4, c4 = (i & 15) * 4;
  const float* p = XP + (size_t)row * 64 + c4;
  float4 s = make_float4(0.f, 0.f, 0.f, 0.f);
#pragma unroll
  for (int sp = 0; sp < NSPLIT; sp++) {
    const float4 v = *(const float4*)(p + (size_t)sp * ROWS * 64);
    s.x += v.x;
    s.y += v.y;
    s.z += v.z;
    s.w += v.w;
  }
  if (c4 == 48) {
    BCv[row] = s.x;
    CCv[row] = s.y;
  }
  union { unsigned short h[4]; uint2 u; } pk;
  pk.h[0] = f2bf(s.x);
  pk.h[1] = f2bf(s.y);
  pk.h[2] = f2bf(s.z);
  pk.h[3] = f2bf(s.w);
  *(uint2*)(DTLRb + (size_t)row * 64 + c4) = pk.u;
}

// ------------------- dt GEMM (K=64) -> DT bf16 only (softplus fused)
// grid (12, 128). 64 rows x 128 cols per block.
__global__ __launch_bounds__(256) void dt_gemm(
    const unsigned short* __restrict__ DTLRb, const unsigned short* __restrict__ DTWb,
    const float* __restrict__ bias, unsigned short* __restrict__ DT) {
  __shared__ unsigned short As[2][64 * 32];
  __shared__ unsigned short Bs[2][128 * 32];
  const int tid = threadIdx.x;
  const int w = tid >> 6, l = tid & 63;
  const int quad = l >> 4, l16 = l & 15;
  const int wrow = (w >> 1) * 32, wcol = (w & 1) * 64;
  const int row0 = blockIdx.y * 64, col0 = blockIdx.x * 128;
  const int srow = w * 16 + (l >> 2);
  const int koff = (l & 3) * 8;

#pragma unroll
  for (int c = 0; c < 2; c++) {
    gld_lds16(DTLRb + (size_t)(row0 + srow) * 64 + c * 32 + koff,
              (char*)As[c] + w * 1024);
#pragma unroll
    for (int r = 0; r < 2; r++)
      gld_lds16(DTWb + (size_t)(col0 + srow + r * 64) * 64 + c * 32 + koff,
                (char*)Bs[c] + r * 4096 + w * 1024);
  }
  __syncthreads();

  f4 acc[2][4];
#pragma unroll
  for (int i = 0; i < 2; i++)
#pragma unroll
    for (int j = 0; j < 4; j++) acc[i][j] = (f4){0.f, 0.f, 0.f, 0.f};

#pragma unroll
  for (int c = 0; c < 2; c++) {
    bfrag af[2], bf[4];
#pragma unroll
    for (int i = 0; i < 2; i++)
      af[i] = *(const bfrag*)(const void*)(As[c] + (wrow + i * 16 + l16) * 32 + quad * 8);
#pragma unroll
    for (int j = 0; j < 4; j++)
      bf[j] = *(const bfrag*)(const void*)(Bs[c] + (wcol + j * 16 + l16) * 32 + quad * 8);
#pragma unroll
    for (int i = 0; i < 2; i++)
#pragma unroll
      for (int j = 0; j < 4; j++)
        acc[i][j] = __builtin_amdgcn_mfma_f32_16x16x32_bf16(af[i], bf[j], acc[i][j], 0, 0, 0);
  }

  float bj[4];
#pragma unroll
  for (int j = 0; j < 4; j++) bj[j] = bias[col0 + wcol + j * 16 + l16];
#pragma unroll
  for (int i = 0; i < 2; i++) {
#pragma unroll
    for (int r = 0; r < 4; r++) {
      const int row = row0 + wrow + i * 16 + quad * 4 + r;
#pragma unroll
      for (int j = 0; j < 4; j++) {
        const int d = col0 + wcol + j * 16 + l16;
        const float s = acc[i][j][r] + bj[j];
        // fast softplus: max(s,0) + log(1 + exp(-|s|)) with hw exp/log
        const float sp = fmaxf(s, 0.f) + __logf(1.f + __expf(-fabsf(s)));
        DT[(size_t)row * DIN + d] = f2bf(sp);
      }
    }
  }
}

// -------------------------------------------------- level schedule (1 block)
__global__ __launch_bounds__(1024) void sched_kernel(
    const int* __restrict__ sidx, const int* __restrict__ spar,
    int* __restrict__ SLOT_NODE, int* __restrict__ SLOT_PNODE,
    int* __restrict__ LSTART, int* __restrict__ NLEV) {
  __shared__ int par[2048], idx[2048], ancA[2048], ancB[2048], rnkA[2048], rnkB[2048];
  __shared__ int dmax;
  const int tid = threadIdx.x;
  for (int i = tid; i < 2048; i += 1024) {
    const int p = spar[i];
    par[i] = p;
    idx[i] = sidx[i];
    ancA[i] = (p < 0) ? -1 : p;
    rnkA[i] = (p < 0) ? 0 : 1;
  }
  if (tid == 0) dmax = 0;
  __syncthreads();
  for (int r = 0; r < 11; r++) {
    int* ca = (r & 1) ? ancB : ancA;
    int* cr = (r & 1) ? rnkB : rnkA;
    int* na = (r & 1) ? ancA : ancB;
    int* nr = (r & 1) ? rnkA : rnkB;
    for (int i = tid; i < 2048; i += 1024) {
      const int a = ca[i], rv = cr[i];
      if (a >= 0) {
        nr[i] = rv + cr[a];
        na[i] = ca[a];
      } else {
        nr[i] = rv;
        na[i] = a;
      }
    }
    __syncthreads();
  }
  for (int i = tid; i < 2048; i += 1024) ancA[i] = 0;
  __syncthreads();
  for (int i = tid; i < 2048; i += 1024) {
    atomicAdd(&ancA[rnkB[i]], 1);
    atomicMax(&dmax, rnkB[i]);
  }
  __syncthreads();
  for (int s = 0; s < 11; s++) {
    const int off = 1 << s;
    int* cur = (s & 1) ? ancB : ancA;
    int* nxt = (s & 1) ? ancA : ancB;
    for (int i = tid; i < 2048; i += 1024) {
      int v = cur[i];
      if (i >= off) v += cur[i - off];
      nxt[i] = v;
    }
    __syncthreads();
  }
  for (int i = tid; i < 2049; i += 1024) {
    const int v = (i == 0) ? 0 : ancB[i - 1];
    LSTART[i] = v;
    if (i < 2048) rnkA[i] = v;
  }
  if (tid == 0) NLEV[0] = dmax + 1;
  __syncthreads();
  for (int i = tid; i < 2048; i += 1024) {
    const int d = rnkB[i];
    const int slot = atomicAdd(&rnkA[d], 1);
    SLOT_NODE[slot] = idx[i];
    const int p = par[i];
    SLOT_PNODE[slot] = (p < 0) ? -1 : idx[p];
  }
}

// ------------------------------------ tree recurrence (dA/dBx fused in-sweep)
// h[node] = exp(dt*negA) * h[parent] + dt*bc*xi, per level.
__global__ __launch_bounds__(256) void recur_kernel(
    const unsigned short* __restrict__ DT, const unsigned short* __restrict__ XI,
    const float* __restrict__ negA, const float* __restrict__ BCv,
    float* __restrict__ H,
    const int* __restrict__ SLOT_NODE, const int* __restrict__ SLOT_PNODE,
    const int* __restrict__ LSTART, const int* __restrict__ NLEV) {
  const int tid = threadIdx.x;
  const int base_c4 = blockIdx.x * 4;
  const int nlev = NLEV[0];
  float4* H4 = (float4*)H;
  for (int L = 0; L < nlev; L++) {
    const int s0 = LSTART[L], s1 = LSTART[L + 1];
    const int items = (s1 - s0) * 4;
    for (int it = tid; it < items; it += 256) {
      const int s = s0 + (it >> 2);
      const int c4 = base_c4 + (it & 3);
      const int node = SLOT_NODE[s];
      const int pn = SLOT_PNODE[s];
      const int b = c4 / 384, d4 = c4 % 384;
      const int row = b * NSEQ + node;
      const ushort4 dtu = *(const ushort4*)(DT + (size_t)row * DIN + d4 * 4);
      const ushort4 xiu = *(const ushort4*)(XI + (size_t)row * DIN + d4 * 4);
      const float4 a4 = *(const float4*)(negA + d4 * 4);
      const float bc = BCv[row];
      float4 hp = make_float4(0.f, 0.f, 0.f, 0.f);
      if (pn >= 0) hp = H4[((size_t)b * NSEQ + pn) * 384 + d4];
      const float t0 = bf2f(dtu.x), t1 = bf2f(dtu.y), t2 = bf2f(dtu.z), t3 = bf2f(dtu.w);
      float4 hv;
      hv.x = fmaf(__expf(t0 * a4.x), hp.x, t0 * bc * bf2f(xiu.x));
      hv.y = fmaf(__expf(t1 * a4.y), hp.y, t1 * bc * bf2f(xiu.y));
      hv.z = fmaf(__expf(t2 * a4.z), hp.z, t2 * bc * bf2f(xiu.z));
      hv.w = fmaf(__expf(t3 * a4.w), hp.w, t3 * bc * bf2f(xiu.w));
      H4[((size_t)row) * 384 + d4] = hv;
    }
    __syncthreads();
  }
}

// --------------------------------------------- y, layernorm, z-gate -> bf16
__global__ __launch_bounds__(256) void ln_kernel(
    const float* __restrict__ H, const float* __restrict__ CCv,
    const unsigned short* __restrict__ XI, const float* __restrict__ Dp,
    const float* __restrict__ gamma, const float* __restrict__ beta,
    const unsigned short* __restrict__ Z, unsigned short* __restrict__ YLN) {
  const int row = blockIdx.x;
  const int tid = threadIdx.x;
  const float C = CCv[row];
  const float* hrow = H + (size_t)row * DIN;
  const unsigned short* xrow = XI + (size_t)row * DIN;
  float y[6];
  float s = 0.f, s2 = 0.f;
#pragma unroll
  for (int i = 0; i < 6; i++) {
    const int d = tid + i * 256;
    const float v = fmaf(hrow[d], C, Dp[d] * bf2f(xrow[d]));
    y[i] = v;
    s += v;
    s2 = fmaf(v, v, s2);
  }
#pragma unroll
  for (int off = 32; off >= 1; off >>= 1) {
    s += __shfl_down(s, off);
    s2 += __shfl_down(s2, off);
  }
  __shared__ float rs[4], rs2[4];
  const int w = tid >> 6;
  if ((tid & 63) == 0) {
    rs[w] = s;
    rs2[w] = s2;
  }
  __syncthreads();
  const float ts = rs[0] + rs[1] + rs[2] + rs[3];
  const float ts2 = rs2[0] + rs2[1] + rs2[2] + rs2[3];
  const float mu = ts * (1.f / 1536.f);
  const float var = ts2 * (1.f / 1536.f) - mu * mu;
  const float inv = rsqrtf(var + 1e-5f);
  unsigned short* yrow = YLN + (size_t)row * DIN;
  const unsigned short* zrow = Z + (size_t)row * DIN;
#pragma unroll
  for (int i = 0; i < 6; i++) {
    const int d = tid + i * 256;
    const float o = (y[i] - mu) * inv * gamma[d] + beta[d];
    yrow[d] = f2bf(o * bf2f(zrow[d]));
  }
}

// ---------------------------------------------------------------------- launch
extern "C" void kernel_launch(void* const* d_in, const int* in_sizes, int n_in,
                              void* d_out, int out_size, void* d_ws, size_t ws_size,
                              hipStream_t stream) {
  const float* x = (const float*)d_in[0];
  const int* sidx = (const int*)d_in[1];
  const int* spar = (const int*)d_in[2];
  const float* in_proj = (const float*)d_in[3];
  const float* x_proj = (const float*)d_in[4];
  const float* dt_proj = (const float*)d_in[5];
  const float* dt_b = (const float*)d_in[6];
  const float* A_log = (const float*)d_in[7];
  const float* Dp = (const float*)d_in[8];
  const float* gamma = (const float*)d_in[9];
  const float* beta = (const float*)d_in[10];
  const float* out_proj = (const float*)d_in[11];
  float* out = (float*)d_out;

  char* p = (char*)d_ws;
  const size_t RC = (size_t)ROWS * DIN;
  unsigned short* XI = (unsigned short*)p;  p += RC * 2;               // 25.2 MB
  unsigned short* Z = (unsigned short*)p;   p += RC * 2;               // 25.2 MB
  unsigned short* DT = (unsigned short*)p;  p += RC * 2;               // 25.2 MB
  float* H = (float*)p;                     p += RC * 4;               // 50.3 MB
  float* XP = (float*)p;                    p += (size_t)NSPLIT * ROWS * 64 * 4;  // 16.8 MB
  unsigned short* DTLRb = (unsigned short*)p; p += (size_t)ROWS * 64 * 2;  // 1 MB
  float* BCv = (float*)p;                   p += ROWS * 4;
  float* CCv = (float*)p;                   p += ROWS * 4;
  float* negA = (float*)p;                  p += DIN * 4;
  unsigned short* Xbf = (unsigned short*)p; p += (size_t)ROWS * DMOD * 2;        // 12.6 MB
  unsigned short* W1t = (unsigned short*)p; p += (size_t)2 * DIN * DMOD * 2;     // 4.7 MB
  unsigned short* W2t = (unsigned short*)p; p += (size_t)DMOD * DIN * 2;         // 2.4 MB
  unsigned short* XPW = (unsigned short*)p; p += (size_t)64 * DIN * 2;
  unsigned short* DTWb = (unsigned short*)p; p += (size_t)DIN * 64 * 2;
  int* ipart = (int*)p;
  int* SLOT_NODE = ipart;
  int* SLOT_PNODE = ipart + 2048;
  int* LSTART = ipart + 4096;
  int* NLEV = ipart + 4096 + 2049;
  unsigned short* YLN = DT;  // DT dead after recur; reuse for LN output (bf16)

  sched_kernel<<<1, 1024, 0, stream>>>(sidx, spar, SLOT_NODE, SLOT_PNODE, LSTART, NLEV);
  cast_bf16_kernel<<<(ROWS * DMOD / 4 + 255) / 256, 256, 0, stream>>>(x, Xbf, ROWS * DMOD / 4);
  transpose_cast_kernel<<<dim3(2 * DIN / 32, DMOD / 32), 256, 0, stream>>>(in_proj, W1t, DMOD, 2 * DIN);
  transpose_cast_kernel<<<dim3(DMOD / 32, DIN / 32), 256, 0, stream>>>(out_proj, W2t, DIN, DMOD);
  xpw_cast_kernel<<<64 * DIN / 256, 256, 0, stream>>>(x_proj, XPW);
  dtw_cast_kernel<<<DIN * 64 / 256, 256, 0, stream>>>(dt_proj, DTWb);
  negexpa_kernel<<<(DIN + 255) / 256, 256, 0, stream>>>(A_log, negA);

  mfma_gemm<1><<<dim3(24, 64), 256, 0, stream>>>(Xbf, W1t, XI, Z, DMOD, DIN);
  xdbl_mfma<<<dim3(NSPLIT, 64), 256, 0, stream>>>(XI, XPW, XP);
  xp_reduce<<<ROWS * 16 / 256, 256, 0, stream>>>(XP, DTLRb, BCv, CCv);
  dt_gemm<<<dim3(12, 128), 256, 0, stream>>>(DTLRb, DTWb, dt_b, DT);
  recur_kernel<<<384, 256, 0, stream>>>(DT, XI, negA, BCv, H, SLOT_NODE, SLOT_PNODE, LSTART, NLEV);
  ln_kernel<<<ROWS, 256, 0, stream>>>(H, CCv, XI, Dp, gamma, beta, Z, YLN);
  mfma_gemm<0><<<dim3(6, 64), 256, 0, stream>>>(YLN, W2t, out, nullptr, DIN, DMOD);
}

// Round 7
// 337.218 us; speedup vs baseline: 3.8250x; 1.0277x over previous
//
#include <hip/hip_runtime.h>
#include <math.h>

// TreeMambaLayer: B=4, N=2048, D_MODEL=768, D_INNER=1536, DT_RANK=48
// Round 7: BK=64 GEMMs (halve barrier stalls, 32 MFMA/iter); H stored bf16
// (recurrence is a contraction, |dA|<1); recur vectorized to 8 bf16/item.

#define ROWS 8192
#define DIN 1536
#define DMOD 768
#define NSEQ 2048
#define DTR 48
#define NSPLIT 8

typedef __bf16 bfrag __attribute__((ext_vector_type(8)));
typedef float f4 __attribute__((ext_vector_type(4)));

__device__ __forceinline__ unsigned short f2bf(float f) {
  unsigned int u = __float_as_uint(f);
  unsigned int r = (u + 0x7fffu + ((u >> 16) & 1u)) >> 16;
  return (unsigned short)r;
}
__device__ __forceinline__ float bf2f(unsigned short h) {
  return __uint_as_float(((unsigned int)h) << 16);
}

__device__ __forceinline__ void gld_lds16(const void* g, void* l) {
  __builtin_amdgcn_global_load_lds((const __attribute__((address_space(1))) void*)g,
                                   (__attribute__((address_space(3))) void*)l, 16, 0, 0);
}

// ------------------------------------------------------------- bf16 MFMA GEMM
// BK=64 (2 chunks of 32), 128x128 tile, 4 waves x 4x4 of 16x16x32.
// MODE 0: C0 = fp32 out (ld = ldc). MODE 1: in_proj -> XI bf16, Z=silu bf16.
template <int MODE>
__global__ __launch_bounds__(256) void mfma_gemm(
    const unsigned short* __restrict__ A, const unsigned short* __restrict__ Bt,
    void* __restrict__ C0v, void* __restrict__ C1v, int K, int ldc) {
  __shared__ unsigned short As[2][128 * 32];
  __shared__ unsigned short Bs[2][128 * 32];
  const int tid = threadIdx.x;
  const int w = tid >> 6, l = tid & 63;
  const int quad = l >> 4, l16 = l & 15;
  const int wrow = (w >> 1) * 64, wcol = (w & 1) * 64;
  const int row0 = blockIdx.y * 128, col0 = blockIdx.x * 128;

  f4 acc[4][4];
#pragma unroll
  for (int i = 0; i < 4; i++)
#pragma unroll
    for (int j = 0; j < 4; j++) acc[i][j] = (f4){0.f, 0.f, 0.f, 0.f};

  const int arow = row0 + w * 16 + (l >> 2);
  const int brow = col0 + w * 16 + (l >> 2);
  const int kcol = (l & 3) * 8;

  for (int k0 = 0; k0 < K; k0 += 64) {
#pragma unroll
    for (int c = 0; c < 2; c++)
#pragma unroll
      for (int r = 0; r < 2; r++) {
        gld_lds16(A + (size_t)(arow + r * 64) * K + k0 + c * 32 + kcol,
                  (char*)As[c] + r * 4096 + w * 1024);
        gld_lds16(Bt + (size_t)(brow + r * 64) * K + k0 + c * 32 + kcol,
                  (char*)Bs[c] + r * 4096 + w * 1024);
      }
    __syncthreads();
#pragma unroll
    for (int c = 0; c < 2; c++) {
      bfrag af[4], bf[4];
#pragma unroll
      for (int i = 0; i < 4; i++)
        af[i] = *(const bfrag*)(const void*)(As[c] + (wrow + i * 16 + l16) * 32 + quad * 8);
#pragma unroll
      for (int j = 0; j < 4; j++)
        bf[j] = *(const bfrag*)(const void*)(Bs[c] + (wcol + j * 16 + l16) * 32 + quad * 8);
#pragma unroll
      for (int i = 0; i < 4; i++)
#pragma unroll
        for (int j = 0; j < 4; j++)
          acc[i][j] = __builtin_amdgcn_mfma_f32_16x16x32_bf16(af[i], bf[j], acc[i][j], 0, 0, 0);
    }
    __syncthreads();
  }

  if (MODE == 0) {
    float* C0 = (float*)C0v;
    const int ccol = col0 + wcol + l16;
#pragma unroll
    for (int i = 0; i < 4; i++) {
      const int rb = row0 + wrow + i * 16 + quad * 4;
#pragma unroll
      for (int j = 0; j < 4; j++)
#pragma unroll
        for (int r = 0; r < 4; r++)
          C0[(size_t)(rb + r) * ldc + ccol + j * 16] = acc[i][j][r];
    }
  } else {
    const bool is_z = (col0 >= DIN);
    unsigned short* dst = is_z ? (unsigned short*)C1v : (unsigned short*)C0v;
    const int cbase = col0 + wcol + l16 - (is_z ? DIN : 0);
#pragma unroll
    for (int i = 0; i < 4; i++) {
      const int rb = row0 + wrow + i * 16 + quad * 4;
#pragma unroll
      for (int j = 0; j < 4; j++)
#pragma unroll
        for (int r = 0; r < 4; r++) {
          float v = acc[i][j][r];
          if (is_z) v = v / (1.f + __expf(-v));
          dst[(size_t)(rb + r) * DIN + cbase + j * 16] = f2bf(v);
        }
    }
  }
}

// ----------------------------------------------------------------- casts
__global__ __launch_bounds__(256) void cast_bf16_kernel(
    const float* __restrict__ in, unsigned short* __restrict__ out, int n4) {
  const int i = (blockIdx.x * 256 + threadIdx.x) * 4;
  if (i < n4 * 4) {
    const float4 v = *(const float4*)(in + i);
    union { unsigned short h[4]; uint2 u; } p;
    p.h[0] = f2bf(v.x);
    p.h[1] = f2bf(v.y);
    p.h[2] = f2bf(v.z);
    p.h[3] = f2bf(v.w);
    *(uint2*)(out + i) = p.u;
  }
}

// W (K x N) fp32 -> Wt (N x K) bf16
__global__ __launch_bounds__(256) void transpose_cast_kernel(
    const float* __restrict__ W, unsigned short* __restrict__ Wt, int K, int N) {
  __shared__ float t[32][33];
  const int n0 = blockIdx.x * 32, k0 = blockIdx.y * 32;
  const int tx = threadIdx.x & 31, ty = threadIdx.x >> 5;
  for (int i = ty; i < 32; i += 8) t[i][tx] = W[(size_t)(k0 + i) * N + n0 + tx];
  __syncthreads();
  for (int i = ty; i < 32; i += 8)
    Wt[(size_t)(n0 + i) * K + k0 + tx] = f2bf(t[tx][i]);
}

// x_proj_w (1536 x 50) fp32 -> XPW (64 x 1536) bf16, cols 50..63 zero
__global__ __launch_bounds__(256) void xpw_cast_kernel(
    const float* __restrict__ W, unsigned short* __restrict__ XPW) {
  const int i = blockIdx.x * 256 + threadIdx.x;  // 64*1536
  const int c = i / 1536, k = i % 1536;
  XPW[i] = (c < 50) ? f2bf(W[(size_t)k * 50 + c]) : (unsigned short)0;
}

// dt_proj_w (48 x 1536) fp32 -> DTWb (1536 x 64) bf16, k 48..63 zero
__global__ __launch_bounds__(256) void dtw_cast_kernel(
    const float* __restrict__ W, unsigned short* __restrict__ DTWb) {
  const int i = blockIdx.x * 256 + threadIdx.x;  // 1536*64
  const int d = i >> 6, k = i & 63;
  DTWb[i] = (k < 48) ? f2bf(W[(size_t)k * DIN + d]) : (unsigned short)0;
}

// negA[d] = -exp(A_log[d])
__global__ __launch_bounds__(256) void negexpa_kernel(
    const float* __restrict__ A_log, float* __restrict__ negA) {
  const int i = blockIdx.x * 256 + threadIdx.x;
  if (i < DIN) negA[i] = -__expf(A_log[i]);
}

// ------------------------------------------------- x_dbl: split-K bf16 MFMA
__global__ __launch_bounds__(256) void xdbl_mfma(
    const unsigned short* __restrict__ XI, const unsigned short* __restrict__ XPW,
    float* __restrict__ XP) {
  __shared__ unsigned short As[128 * 32];
  __shared__ unsigned short Bs[64 * 32];
  const int tid = threadIdx.x;
  const int w = tid >> 6, l = tid & 63;
  const int quad = l >> 4, l16 = l & 15;
  const int split = blockIdx.x;
  const int row0 = blockIdx.y * 128;
  const int kbase = split * (DIN / NSPLIT);  // 192

  f4 acc[2][4];
#pragma unroll
  for (int i = 0; i < 2; i++)
#pragma unroll
    for (int j = 0; j < 4; j++) acc[i][j] = (f4){0.f, 0.f, 0.f, 0.f};

  const int srow = w * 16 + (l >> 2);
  const int kcol = (l & 3) * 8;

  for (int c = 0; c < 6; c++) {
    const int k0 = kbase + c * 32;
#pragma unroll
    for (int r = 0; r < 2; r++) {
      gld_lds16(XI + (size_t)(row0 + srow + r * 64) * DIN + k0 + kcol,
                (char*)As + r * 4096 + w * 1024);
    }
    gld_lds16(XPW + (size_t)srow * DIN + k0 + kcol, (char*)Bs + w * 1024);
    __syncthreads();
    bfrag af[2], bf[4];
#pragma unroll
    for (int i = 0; i < 2; i++)
      af[i] = *(const bfrag*)(const void*)(As + (w * 32 + i * 16 + l16) * 32 + quad * 8);
#pragma unroll
    for (int j = 0; j < 4; j++)
      bf[j] = *(const bfrag*)(const void*)(Bs + (j * 16 + l16) * 32 + quad * 8);
#pragma unroll
    for (int i = 0; i < 2; i++)
#pragma unroll
      for (int j = 0; j < 4; j++)
        acc[i][j] = __builtin_amdgcn_mfma_f32_16x16x32_bf16(af[i], bf[j], acc[i][j], 0, 0, 0);
    __syncthreads();
  }

  float* dst = XP + (size_t)split * ROWS * 64 + (size_t)row0 * 64;
#pragma unroll
  for (int i = 0; i < 2; i++) {
    const int rb = w * 32 + i * 16 + quad * 4;
#pragma unroll
    for (int j = 0; j < 4; j++) {
      const int col = j * 16 + l16;
#pragma unroll
      for (int r = 0; r < 4; r++) dst[(size_t)(rb + r) * 64 + col] = acc[i][j][r];
    }
  }
}

// -------------------------- reduce XP partials -> DTLRb bf16 + BC/CC fp32
__global__ __launch_bounds__(256) void xp_reduce(
    const float* __restrict__ XP, unsigned short* __restrict__ DTLRb,
    float* __restrict__ BCv, float* __restrict__ CCv) {
  const int i = blockIdx.x * 256 + threadIdx.x;  // 8192*16
  const int row = i >> 4, c4 = (i & 15) * 4;
  const float* p = XP + (size_t)row * 64 + c4;
  float4 s = make_float4(0.f, 0.f, 0.f, 0.f);
#pragma unroll
  for (int sp = 0; sp < NSPLIT; sp++) {
    const float4 v = *(const float4*)(p + (size_t)sp * ROWS * 64);
    s.x += v.x;
    s.y += v.y;
    s.z += v.z;
    s.w += v.w;
  }
  if (c4 == 48) {
    BCv[row] = s.x;
    CCv[row] = s.y;
  }
  union { unsigned short h[4]; uint2 u; } pk;
  pk.h[0] = f2bf(s.x);
  pk.h[1] = f2bf(s.y);
  pk.h[2] = f2bf(s.z);
  pk.h[3] = f2bf(s.w);
  *(uint2*)(DTLRb + (size_t)row * 64 + c4) = pk.u;
}

// ------------------- dt GEMM (K=64) -> DT bf16 only (softplus fused)
// grid (12, 128). 64 rows x 128 cols per block.
__global__ __launch_bounds__(256) void dt_gemm(
    const unsigned short* __restrict__ DTLRb, const unsigned short* __restrict__ DTWb,
    const float* __restrict__ bias, unsigned short* __restrict__ DT) {
  __shared__ unsigned short As[2][64 * 32];
  __shared__ unsigned short Bs[2][128 * 32];
  const int tid = threadIdx.x;
  const int w = tid >> 6, l = tid & 63;
  const int quad = l >> 4, l16 = l & 15;
  const int wrow = (w >> 1) * 32, wcol = (w & 1) * 64;
  const int row0 = blockIdx.y * 64, col0 = blockIdx.x * 128;
  const int srow = w * 16 + (l >> 2);
  const int koff = (l & 3) * 8;

#pragma unroll
  for (int c = 0; c < 2; c++) {
    gld_lds16(DTLRb + (size_t)(row0 + srow) * 64 + c * 32 + koff,
              (char*)As[c] + w * 1024);
#pragma unroll
    for (int r = 0; r < 2; r++)
      gld_lds16(DTWb + (size_t)(col0 + srow + r * 64) * 64 + c * 32 + koff,
                (char*)Bs[c] + r * 4096 + w * 1024);
  }
  __syncthreads();

  f4 acc[2][4];
#pragma unroll
  for (int i = 0; i < 2; i++)
#pragma unroll
    for (int j = 0; j < 4; j++) acc[i][j] = (f4){0.f, 0.f, 0.f, 0.f};

#pragma unroll
  for (int c = 0; c < 2; c++) {
    bfrag af[2], bf[4];
#pragma unroll
    for (int i = 0; i < 2; i++)
      af[i] = *(const bfrag*)(const void*)(As[c] + (wrow + i * 16 + l16) * 32 + quad * 8);
#pragma unroll
    for (int j = 0; j < 4; j++)
      bf[j] = *(const bfrag*)(const void*)(Bs[c] + (wcol + j * 16 + l16) * 32 + quad * 8);
#pragma unroll
    for (int i = 0; i < 2; i++)
#pragma unroll
      for (int j = 0; j < 4; j++)
        acc[i][j] = __builtin_amdgcn_mfma_f32_16x16x32_bf16(af[i], bf[j], acc[i][j], 0, 0, 0);
  }

  float bj[4];
#pragma unroll
  for (int j = 0; j < 4; j++) bj[j] = bias[col0 + wcol + j * 16 + l16];
#pragma unroll
  for (int i = 0; i < 2; i++) {
#pragma unroll
    for (int r = 0; r < 4; r++) {
      const int row = row0 + wrow + i * 16 + quad * 4 + r;
#pragma unroll
      for (int j = 0; j < 4; j++) {
        const int d = col0 + wcol + j * 16 + l16;
        const float s = acc[i][j][r] + bj[j];
        const float sp = fmaxf(s, 0.f) + __logf(1.f + __expf(-fabsf(s)));
        DT[(size_t)row * DIN + d] = f2bf(sp);
      }
    }
  }
}

// -------------------------------------------------- level schedule (1 block)
__global__ __launch_bounds__(1024) void sched_kernel(
    const int* __restrict__ sidx, const int* __restrict__ spar,
    int* __restrict__ SLOT_NODE, int* __restrict__ SLOT_PNODE,
    int* __restrict__ LSTART, int* __restrict__ NLEV) {
  __shared__ int par[2048], idx[2048], ancA[2048], ancB[2048], rnkA[2048], rnkB[2048];
  __shared__ int dmax;
  const int tid = threadIdx.x;
  for (int i = tid; i < 2048; i += 1024) {
    const int p = spar[i];
    par[i] = p;
    idx[i] = sidx[i];
    ancA[i] = (p < 0) ? -1 : p;
    rnkA[i] = (p < 0) ? 0 : 1;
  }
  if (tid == 0) dmax = 0;
  __syncthreads();
  for (int r = 0; r < 11; r++) {
    int* ca = (r & 1) ? ancB : ancA;
    int* cr = (r & 1) ? rnkB : rnkA;
    int* na = (r & 1) ? ancA : ancB;
    int* nr = (r & 1) ? rnkA : rnkB;
    for (int i = tid; i < 2048; i += 1024) {
      const int a = ca[i], rv = cr[i];
      if (a >= 0) {
        nr[i] = rv + cr[a];
        na[i] = ca[a];
      } else {
        nr[i] = rv;
        na[i] = a;
      }
    }
    __syncthreads();
  }
  for (int i = tid; i < 2048; i += 1024) ancA[i] = 0;
  __syncthreads();
  for (int i = tid; i < 2048; i += 1024) {
    atomicAdd(&ancA[rnkB[i]], 1);
    atomicMax(&dmax, rnkB[i]);
  }
  __syncthreads();
  for (int s = 0; s < 11; s++) {
    const int off = 1 << s;
    int* cur = (s & 1) ? ancB : ancA;
    int* nxt = (s & 1) ? ancA : ancB;
    for (int i = tid; i < 2048; i += 1024) {
      int v = cur[i];
      if (i >= off) v += cur[i - off];
      nxt[i] = v;
    }
    __syncthreads();
  }
  for (int i = tid; i < 2049; i += 1024) {
    const int v = (i == 0) ? 0 : ancB[i - 1];
    LSTART[i] = v;
    if (i < 2048) rnkA[i] = v;
  }
  if (tid == 0) NLEV[0] = dmax + 1;
  __syncthreads();
  for (int i = tid; i < 2048; i += 1024) {
    const int d = rnkB[i];
    const int slot = atomicAdd(&rnkA[d], 1);
    SLOT_NODE[slot] = idx[i];
    const int p = par[i];
    SLOT_PNODE[slot] = (p < 0) ? -1 : idx[p];
  }
}

// ------------------------------------ tree recurrence (dA/dBx fused, h bf16)
// h[node] = exp(dt*negA) * h[parent] + dt*bc*xi per level; 8 bf16 per item.
__global__ __launch_bounds__(256) void recur_kernel(
    const unsigned short* __restrict__ DT, const unsigned short* __restrict__ XI,
    const float* __restrict__ negA, const float* __restrict__ BCv,
    unsigned short* __restrict__ Hb,
    const int* __restrict__ SLOT_NODE, const int* __restrict__ SLOT_PNODE,
    const int* __restrict__ LSTART, const int* __restrict__ NLEV) {
  const int tid = threadIdx.x;
  const int base_c8 = blockIdx.x * 2;  // 768 chunks of 8 bf16 (192/batch x 4)
  const int nlev = NLEV[0];
  for (int L = 0; L < nlev; L++) {
    const int s0 = LSTART[L], s1 = LSTART[L + 1];
    const int items = (s1 - s0) * 2;
    for (int it = tid; it < items; it += 256) {
      const int s = s0 + (it >> 1);
      const int c8 = base_c8 + (it & 1);
      const int node = SLOT_NODE[s];
      const int pn = SLOT_PNODE[s];
      const int b = c8 / 192, d8 = c8 % 192;
      const size_t row = (size_t)b * NSEQ + node;
      const size_t off = row * DIN + d8 * 8;
      union { uint4 u; unsigned short h[8]; } dtu, xiu, hpu, hvu;
      dtu.u = *(const uint4*)(DT + off);
      xiu.u = *(const uint4*)(XI + off);
      const float4 a0 = *(const float4*)(negA + d8 * 8);
      const float4 a1 = *(const float4*)(negA + d8 * 8 + 4);
      const float bc = BCv[row];
      float hp[8];
      if (pn >= 0) {
        hpu.u = *(const uint4*)(Hb + ((size_t)b * NSEQ + pn) * DIN + d8 * 8);
#pragma unroll
        for (int e = 0; e < 8; e++) hp[e] = bf2f(hpu.h[e]);
      } else {
#pragma unroll
        for (int e = 0; e < 8; e++) hp[e] = 0.f;
      }
      const float an[8] = {a0.x, a0.y, a0.z, a0.w, a1.x, a1.y, a1.z, a1.w};
#pragma unroll
      for (int e = 0; e < 8; e++) {
        const float t = bf2f(dtu.h[e]);
        const float hv = fmaf(__expf(t * an[e]), hp[e], t * bc * bf2f(xiu.h[e]));
        hvu.h[e] = f2bf(hv);
      }
      *(uint4*)(Hb + off) = hvu.u;
    }
    __syncthreads();
  }
}

// --------------------------------------------- y, layernorm, z-gate -> bf16
__global__ __launch_bounds__(256) void ln_kernel(
    const unsigned short* __restrict__ Hb, const float* __restrict__ CCv,
    const unsigned short* __restrict__ XI, const float* __restrict__ Dp,
    const float* __restrict__ gamma, const float* __restrict__ beta,
    const unsigned short* __restrict__ Z, unsigned short* __restrict__ YLN) {
  const int row = blockIdx.x;
  const int tid = threadIdx.x;
  const float C = CCv[row];
  const unsigned short* hrow = Hb + (size_t)row * DIN;
  const unsigned short* xrow = XI + (size_t)row * DIN;
  float y[6];
  float s = 0.f, s2 = 0.f;
#pragma unroll
  for (int i = 0; i < 6; i++) {
    const int d = tid + i * 256;
    const float v = fmaf(bf2f(hrow[d]), C, Dp[d] * bf2f(xrow[d]));
    y[i] = v;
    s += v;
    s2 = fmaf(v, v, s2);
  }
#pragma unroll
  for (int off = 32; off >= 1; off >>= 1) {
    s += __shfl_down(s, off);
    s2 += __shfl_down(s2, off);
  }
  __shared__ float rs[4], rs2[4];
  const int w = tid >> 6;
  if ((tid & 63) == 0) {
    rs[w] = s;
    rs2[w] = s2;
  }
  __syncthreads();
  const float ts = rs[0] + rs[1] + rs[2] + rs[3];
  const float ts2 = rs2[0] + rs2[1] + rs2[2] + rs2[3];
  const float mu = ts * (1.f / 1536.f);
  const float var = ts2 * (1.f / 1536.f) - mu * mu;
  const float inv = rsqrtf(var + 1e-5f);
  unsigned short* yrow = YLN + (size_t)row * DIN;
  const unsigned short* zrow = Z + (size_t)row * DIN;
#pragma unroll
  for (int i = 0; i < 6; i++) {
    const int d = tid + i * 256;
    const float o = (y[i] - mu) * inv * gamma[d] + beta[d];
    yrow[d] = f2bf(o * bf2f(zrow[d]));
  }
}

// ---------------------------------------------------------------------- launch
extern "C" void kernel_launch(void* const* d_in, const int* in_sizes, int n_in,
                              void* d_out, int out_size, void* d_ws, size_t ws_size,
                              hipStream_t stream) {
  const float* x = (const float*)d_in[0];
  const int* sidx = (const int*)d_in[1];
  const int* spar = (const int*)d_in[2];
  const float* in_proj = (const float*)d_in[3];
  const float* x_proj = (const float*)d_in[4];
  const float* dt_proj = (const float*)d_in[5];
  const float* dt_b = (const float*)d_in[6];
  const float* A_log = (const float*)d_in[7];
  const float* Dp = (const float*)d_in[8];
  const float* gamma = (const float*)d_in[9];
  const float* beta = (const float*)d_in[10];
  const float* out_proj = (const float*)d_in[11];
  float* out = (float*)d_out;

  char* p = (char*)d_ws;
  const size_t RC = (size_t)ROWS * DIN;
  unsigned short* XI = (unsigned short*)p;  p += RC * 2;               // 25.2 MB
  unsigned short* Z = (unsigned short*)p;   p += RC * 2;               // 25.2 MB
  unsigned short* DT = (unsigned short*)p;  p += RC * 2;               // 25.2 MB
  unsigned short* Hb = (unsigned short*)p;  p += RC * 2;               // 25.2 MB
  float* XP = (float*)p;                    p += (size_t)NSPLIT * ROWS * 64 * 4;  // 16.8 MB
  unsigned short* DTLRb = (unsigned short*)p; p += (size_t)ROWS * 64 * 2;  // 1 MB
  float* BCv = (float*)p;                   p += ROWS * 4;
  float* CCv = (float*)p;                   p += ROWS * 4;
  float* negA = (float*)p;                  p += DIN * 4;
  unsigned short* Xbf = (unsigned short*)p; p += (size_t)ROWS * DMOD * 2;        // 12.6 MB
  unsigned short* W1t = (unsigned short*)p; p += (size_t)2 * DIN * DMOD * 2;     // 4.7 MB
  unsigned short* W2t = (unsigned short*)p; p += (size_t)DMOD * DIN * 2;         // 2.4 MB
  unsigned short* XPW = (unsigned short*)p; p += (size_t)64 * DIN * 2;
  unsigned short* DTWb = (unsigned short*)p; p += (size_t)DIN * 64 * 2;
  int* ipart = (int*)p;
  int* SLOT_NODE = ipart;
  int* SLOT_PNODE = ipart + 2048;
  int* LSTART = ipart + 4096;
  int* NLEV = ipart + 4096 + 2049;
  unsigned short* YLN = DT;  // DT dead after recur; reuse for LN output (bf16)

  sched_kernel<<<1, 1024, 0, stream>>>(sidx, spar, SLOT_NODE, SLOT_PNODE, LSTART, NLEV);
  cast_bf16_kernel<<<(ROWS * DMOD / 4 + 255) / 256, 256, 0, stream>>>(x, Xbf, ROWS * DMOD / 4);
  transpose_cast_kernel<<<dim3(2 * DIN / 32, DMOD / 32), 256, 0, stream>>>(in_proj, W1t, DMOD, 2 * DIN);
  transpose_cast_kernel<<<dim3(DMOD / 32, DIN / 32), 256, 0, stream>>>(out_proj, W2t, DIN, DMOD);
  xpw_cast_kernel<<<64 * DIN / 256, 256, 0, stream>>>(x_proj, XPW);
  dtw_cast_kernel<<<DIN * 64 / 256, 256, 0, stream>>>(dt_proj, DTWb);
  negexpa_kernel<<<(DIN + 255) / 256, 256, 0, stream>>>(A_log, negA);

  mfma_gemm<1><<<dim3(24, 64), 256, 0, stream>>>(Xbf, W1t, XI, Z, DMOD, DIN);
  xdbl_mfma<<<dim3(NSPLIT, 64), 256, 0, stream>>>(XI, XPW, XP);
  xp_reduce<<<ROWS * 16 / 256, 256, 0, stream>>>(XP, DTLRb, BCv, CCv);
  dt_gemm<<<dim3(12, 128), 256, 0, stream>>>(DTLRb, DTWb, dt_b, DT);
  recur_kernel<<<384, 256, 0, stream>>>(DT, XI, negA, BCv, Hb, SLOT_NODE, SLOT_PNODE, LSTART, NLEV);
  ln_kernel<<<ROWS, 256, 0, stream>>>(Hb, CCv, XI, Dp, gamma, beta, Z, YLN);
  mfma_gemm<0><<<dim3(6, 64), 256, 0, stream>>>(YLN, W2t, out, nullptr, DIN, DMOD);
}